// Round 9
// baseline (240.226 us; speedup 1.0000x reference)
//
#include <hip/hip_runtime.h>

typedef unsigned short u16;
typedef __bf16 bf8 __attribute__((ext_vector_type(8)));
typedef float f4 __attribute__((ext_vector_type(4)));

#define E_EDGES 32768
#define N_NODES 4096
// col layout of w (WNUM=6400): A[u<64][w<64] @0, B[u<64][w<16] @4096, C[u<16][w<16] @5120, D[u<16][w<64] @5376
// tile = 16 cols x 128 k = 4KB; group g covers tiles 4g..4g+3; A g<64, B 64..79, C 80..83, D 84..99
#define N0_CONST 0.1118033988749895f       // sqrt(1/80); also equals N1*INV_SQRT3
#define INV_SQRT3_CONST 0.5773502691896258f

#define SB0() __builtin_amdgcn_sched_barrier(0)

__device__ __forceinline__ u16 f2bf(float f) {
    unsigned u = __float_as_uint(f);
    u += 0x7FFFu + ((u >> 16) & 1u);   // RNE
    return (u16)(u >> 16);
}

__device__ __forceinline__ void gld16(const u16* g, u16* l) {
    __builtin_amdgcn_global_load_lds((const __attribute__((address_space(1))) void*)g,
                                     (__attribute__((address_space(3))) void*)l, 16, 0, 0);
}

__device__ __forceinline__ void gld16f(const float* g, float* l) {
    __builtin_amdgcn_global_load_lds((const __attribute__((address_space(1))) void*)g,
                                     (__attribute__((address_space(3))) void*)l, 16, 0, 0);
}

// Weight prep + src-degree histogram, one launch (unchanged from round 8)
__global__ __launch_bounds__(256) void k_prep(const float* __restrict__ W2, const float* __restrict__ W1,
                                              const int* __restrict__ edge_index,
                                              u16* __restrict__ w2s, u16* __restrict__ w1t,
                                              int* __restrict__ deg) {
    int b = blockIdx.x;
    int tid = threadIdx.x;
    if (b < 400) {
        __shared__ float w2l[128][17];           // [k][c], +1 pad
        {
            int k = tid >> 1, c8 = (tid & 1) * 8;
            const float* src = W2 + (size_t)k * 6400 + b * 16 + c8;
            float tmpf[8];
#pragma unroll
            for (int j = 0; j < 8; j++) tmpf[j] = src[j];
#pragma unroll
            for (int j = 0; j < 8; j++) w2l[k][c8 + j] = tmpf[j];
        }
        __syncthreads();
        int ks = tid >> 6, l = tid & 63;
        int el = l & 15, q4 = l >> 4;
        u16 tmp[8];
#pragma unroll
        for (int j = 0; j < 8; j++)
            tmp[j] = f2bf(w2l[ks * 32 + q4 * 8 + j][el]);
        *(uint4*)(w2s + b * 2048 + ks * 512 + l * 8) = *(uint4*)tmp;
    } else if (b < 416) {
        int t = (b - 400) * 256 + tid;
#pragma unroll
        for (int i = 0; i < 4; i++) {
            int idx = t * 4 + i;                // idx = c*128 + k
            int c = idx >> 7, k = idx & 127;
            w1t[idx] = f2bf(W1[k * 128 + c]);
        }
    } else {
        int t = (b - 416) * 256 + tid;          // 128 blocks * 256 = 32768 = E
        atomicAdd(&deg[edge_index[t]], 1);
    }
}

// Exclusive scan of deg[4096] -> ptr[0..4096] and cursor copy. 1 block, 64 threads.
__global__ void k_scan(const int* __restrict__ deg, int* __restrict__ ptr, int* __restrict__ cursor) {
    int t = threadIdx.x;           // 0..63
    int base = t * 64;
    int s = 0;
    for (int i = 0; i < 64; i++) s += deg[base + i];
    int x = s;
#pragma unroll
    for (int d = 1; d < 64; d <<= 1) {
        int y = __shfl_up(x, d, 64);
        if (t >= d) x += y;
    }
    int run = x - s;               // exclusive prefix
    for (int i = 0; i < 64; i++) {
        ptr[base + i] = run;
        cursor[base + i] = run;
        run += deg[base + i];
    }
    if (t == 63) ptr[4096] = run;
}

// h = relu(edge_attr @ W1 + b1), stored bf16 [E][128]; also fills CSR edge-id list via cursor
__global__ __launch_bounds__(256) void k_h(const float* __restrict__ ea,
                                           const u16* __restrict__ w1t,
                                           const float* __restrict__ b1,
                                           const int* __restrict__ edge_index,
                                           int* __restrict__ cursor,
                                           int* __restrict__ eids,
                                           u16* __restrict__ h) {
    __shared__ alignas(16) u16 ea_s[64][128];
    int tid = threadIdx.x;
    int e0 = blockIdx.x * 64;
    if (tid < 64) {                // CSR fill for this block's 64 edges
        int ge = e0 + tid;
        int s = edge_index[ge];
        int pos = atomicAdd(&cursor[s], 1);
        eids[pos] = ge;
    }
    {
        int e = tid >> 2, q = tid & 3;
        const float4* src = (const float4*)(ea + (size_t)(e0 + e) * 128 + q * 32);
#pragma unroll
        for (int i = 0; i < 8; i++) {
            float4 f = src[i];
            int c = q * 32 + i * 4;
            ea_s[e][c + 0] = f2bf(f.x); ea_s[e][c + 1] = f2bf(f.y);
            ea_s[e][c + 2] = f2bf(f.z); ea_s[e][c + 3] = f2bf(f.w);
        }
    }
    __syncthreads();
    int lane = tid & 63, wave = tid >> 6;
    int el = lane & 15, q4 = lane >> 4;
    f4 acc[4][2];
#pragma unroll
    for (int m = 0; m < 4; m++)
#pragma unroll
        for (int nt = 0; nt < 2; nt++) acc[m][nt] = (f4){0.f, 0.f, 0.f, 0.f};
#pragma unroll
    for (int ks = 0; ks < 4; ks++) {
        bf8 a[4], b[2];
#pragma unroll
        for (int m = 0; m < 4; m++) a[m] = *(const bf8*)&ea_s[m * 16 + el][ks * 32 + q4 * 8];
#pragma unroll
        for (int nt = 0; nt < 2; nt++) {
            int n = wave * 32 + nt * 16 + el;
            b[nt] = *(const bf8*)(w1t + n * 128 + ks * 32 + q4 * 8);
        }
#pragma unroll
        for (int m = 0; m < 4; m++)
#pragma unroll
            for (int nt = 0; nt < 2; nt++)
                acc[m][nt] = __builtin_amdgcn_mfma_f32_16x16x32_bf16(a[m], b[nt], acc[m][nt], 0, 0, 0);
    }
#pragma unroll
    for (int m = 0; m < 4; m++)
#pragma unroll
        for (int nt = 0; nt < 2; nt++) {
            int n = wave * 32 + nt * 16 + el;
            float bias = b1[n];
#pragma unroll
            for (int r = 0; r < 4; r++) {
                int e = e0 + m * 16 + q4 * 4 + r;
                float v = fmaxf(acc[m][nt][r] + bias, 0.f);
                h[(size_t)e * 128 + n] = f2bf(v);
            }
        }
}

// Fused: w = h@W2+b2 tile-by-tile -> contraction -> tp[E][112].
// ROUND-9: 256 blocks x 128 edges, 8 waves. Wave = (tile tl=w&3, edge-half eh=w>>2, 64 edges).
// Per step the block stages ALL 4 tiles (16KB) into LDS via global_load_lds ONCE (L2 traffic
// 410MB = 1/4 of round 8's 1.64GB); each wave ds_reads ONLY its own tile (no LDS redundancy).
// Pipeline = round-3's VERIFIED counted-vmcnt machinery: 3 VMEM ops/wave/step (2 tile gld16 +
// 1 clamped full-wave bias gld16), 3 buffers depth-2, vmcnt(3) steady / vmcnt(0) peeled tail,
// one raw s_barrier per step, SB0 fences (rule #18). Contraction = round-4's VERIFIED nt=0..3
// code with ebase = eh*64. Epilogue: FLAT staging (round-7 lesson): out0 8192<=8320 floats in
// sT, vflat 6144<=6240 in vT. LDS 156.2KB -> 1 block/CU; VGPR ~170 <= 256 cap.
__global__ __launch_bounds__(512, 2) void k_main(const u16* __restrict__ w2s,
                                                 const u16* __restrict__ hgl,
                                                 const float* __restrict__ b2,
                                                 const float* __restrict__ node_attr,
                                                 const int* __restrict__ edge_index,
                                                 const float* __restrict__ edge_sh,
                                                 float* __restrict__ tp) {
    __shared__ alignas(16) u16 stage[3][8192];      // 49152B: [buf][tile*2048], fragment-order
    __shared__ alignas(16) float biasb[3][256];     // 3072B: b2[64g..64g+64) in [0..64); rest filler
    __shared__ alignas(16) union {
        u16 h[128][136];                            // 34816B (prologue; +8 pad)
        struct { float bcB[128][17]; float bcC[3][128][17]; } bc;   // 34816B
    } ovl;
    __shared__ float sT[64][130];             // 33280B s[u][e]; epilogue: out0 FLAT [e*64+c] (8192)
    __shared__ float vT[3][16][130];          // 24960B v[i][u][e]; epilogue: vflat [e*48+cr] (6144)
    __shared__ float pT[16][130];             // 8320B  INV_SQRT3*(v.sh1)[u][e]
    __shared__ float sh0_s[128];
    __shared__ float sh1_s[3][128];
    __shared__ int dst_s[128];

    int tid = threadIdx.x;
    int e0 = blockIdx.x * 128;
    int lane = tid & 63, wave = tid >> 6;     // wave 0..7
    int tl = wave & 3, eh = wave >> 2;        // tile-in-group / edge-half
    int el = lane & 15, q4 = lane >> 4;
    int ebase = eh * 64;

    // issue one step's 3 VMEM ops (identical count/order on every wave -> vmcnt math holds)
    auto issue_step = [&](int i) {
        int g = (i < 20) ? 64 + i : (i < 84 ? i - 20 : i);   // phase order B,C,A,D
        int buf = i % 3;
        int tIdx = tid >> 7;                  // tile 0..3 (wave-pair uniform)
        int off = (tid & 127) * 8;            // u16 offset within tile half-stripe
        const u16* gp = w2s + (size_t)(4 * g + tIdx) * 2048 + off;
        u16* lp = stage[buf] + tIdx * 2048 + off;
        gld16(gp, lp);
        gld16(gp + 1024, lp + 1024);
        int boff = g * 64 + lane * 4;         // full-wave clamped bias DMA (verified r3 pattern)
        boff = boff < 6396 ? boff : 6396;
        gld16f(b2 + boff, &biasb[buf][lane * 4]);
    };

    // prologue prefetch: steps 0,1 in flight under the whole prologue
    issue_step(0); issue_step(1);

    // phase 1: edge meta
    if (tid < 128) {
        int ge = e0 + tid;
        dst_s[tid] = edge_index[E_EDGES + ge];
        float4 sh = *(const float4*)(edge_sh + (size_t)ge * 4);
        sh0_s[tid] = sh.x; sh1_s[0][tid] = sh.y; sh1_s[1][tid] = sh.z; sh1_s[2][tid] = sh.w;
    }
    __syncthreads();

    // phase 2: node features (transposed into LDS) + h tile into ovl.h; 4 threads/edge
    {
        int e = tid >> 2, q = tid & 3;        // e 0..127
        int dst = dst_s[e];
        const float* xp = node_attr + (size_t)dst * 112;
#pragma unroll
        for (int i = 0; i < 4; i++) {
            float4 f = *(const float4*)(xp + q * 16 + i * 4);
            int u = q * 16 + i * 4;
            sT[u + 0][e] = f.x; sT[u + 1][e] = f.y; sT[u + 2][e] = f.z; sT[u + 3][e] = f.w;
        }
        float vv[12];
#pragma unroll
        for (int i = 0; i < 3; i++) {
            float4 f = *(const float4*)(xp + 64 + q * 12 + i * 4);
            vv[i * 4 + 0] = f.x; vv[i * 4 + 1] = f.y; vv[i * 4 + 2] = f.z; vv[i * 4 + 3] = f.w;
        }
        float s1x = sh1_s[0][e], s1y = sh1_s[1][e], s1z = sh1_s[2][e];
#pragma unroll
        for (int u = 0; u < 4; u++) {
            float xa = vv[u * 3 + 0], xb = vv[u * 3 + 1], xc = vv[u * 3 + 2];
            int uu = q * 4 + u;
            vT[0][uu][e] = xa; vT[1][uu][e] = xb; vT[2][uu][e] = xc;
            pT[uu][e] = INV_SQRT3_CONST * (xa * s1x + xb * s1y + xc * s1z);
        }
        const uint4* hsrc = (const uint4*)(hgl + (size_t)(e0 + e) * 128) + q * 4;
        uint4* hdst = (uint4*)(&ovl.h[e][q * 32]);
#pragma unroll
        for (int i = 0; i < 4; i++) hdst[i] = hsrc[i];
    }
    __syncthreads();

    // h B-fragments for this wave's 4 edge-groups (64 VGPRs) + per-lane sh0
    bf8 hbf[4][4];
#pragma unroll
    for (int nt = 0; nt < 4; nt++)
#pragma unroll
        for (int ks = 0; ks < 4; ks++)
            hbf[nt][ks] = *(const bf8*)&ovl.h[ebase + nt * 16 + el][ks * 32 + q4 * 8];
    float sh0n4[4];
#pragma unroll
    for (int nt = 0; nt < 4; nt++) sh0n4[nt] = sh0_s[ebase + nt * 16 + el];
    __syncthreads();   // everyone done reading ovl.h -> becomes bc scratch

    // zero bc scratch (34816B = 8704 floats)
    for (int idx = tid; idx < 8704; idx += 512) ((float*)&ovl.bc)[idx] = 0.f;
    __syncthreads();   // bc zeroed before any wave's atomics; vmcnt drained (prologue ok)

    auto consume = [&](int i, f4 (&wf)[4]) {
        int buf = i % 3;
        const u16* tb = stage[buf] + tl * 2048 + lane * 8;
        bf8 a0 = *(const bf8*)(tb);
        bf8 a1 = *(const bf8*)(tb + 512);
        bf8 a2 = *(const bf8*)(tb + 1024);
        bf8 a3 = *(const bf8*)(tb + 1536);
        float4 bb = *(const float4*)&biasb[buf][tl * 16 + q4 * 4];
#pragma unroll
        for (int nt = 0; nt < 4; nt++) wf[nt] = (f4){bb.x, bb.y, bb.z, bb.w};
#pragma unroll
        for (int nt = 0; nt < 4; nt++) wf[nt] = __builtin_amdgcn_mfma_f32_16x16x32_bf16(a0, hbf[nt][0], wf[nt], 0, 0, 0);
#pragma unroll
        for (int nt = 0; nt < 4; nt++) wf[nt] = __builtin_amdgcn_mfma_f32_16x16x32_bf16(a1, hbf[nt][1], wf[nt], 0, 0, 0);
#pragma unroll
        for (int nt = 0; nt < 4; nt++) wf[nt] = __builtin_amdgcn_mfma_f32_16x16x32_bf16(a2, hbf[nt][2], wf[nt], 0, 0, 0);
#pragma unroll
        for (int nt = 0; nt < 4; nt++) wf[nt] = __builtin_amdgcn_mfma_f32_16x16x32_bf16(a3, hbf[nt][3], wf[nt], 0, 0, 0);
    };
    // per lane: wf[nt][r] = w[edge = ebase+nt*16+el][col-in-tile = q4*4+r]

    // steady-state step: wait own step's 3 ops (1 newer step in flight), 1 barrier, prefetch i+2
    auto pipe = [&](int i, f4 (&wf)[4]) {
        SB0();
        asm volatile("s_waitcnt vmcnt(3)" ::: "memory");
        __builtin_amdgcn_s_barrier();
        SB0();
        if (i + 2 < 100) issue_step(i + 2);
        consume(i, wf);
    };

    f4 wf[4];

    // ---- B phase (i=0..15, g=64+i, u=4*i+tl; out col w = q4*4+r)
    {
        f4 accBn[4];
#pragma unroll
        for (int nt = 0; nt < 4; nt++) accBn[nt] = (f4){0.f, 0.f, 0.f, 0.f};
        for (int ib = 0; ib < 16; ib++) {
            pipe(ib, wf);
            int u = 4 * ib + tl;
#pragma unroll
            for (int nt = 0; nt < 4; nt++) {
                float f = sT[u][ebase + nt * 16 + el];
                accBn[nt] += f * wf[nt];
            }
        }
#pragma unroll
        for (int nt = 0; nt < 4; nt++)
#pragma unroll
            for (int r = 0; r < 4; r++)
                atomicAdd(&ovl.bc.bcB[ebase + nt * 16 + el][q4 * 4 + r], accBn[nt][r]);
    }

    // ---- C phase (i=16..19, g=80+(i-16), u=4*(i-16)+tl)
    {
        f4 accCn[3][4];
#pragma unroll
        for (int i3 = 0; i3 < 3; i3++)
#pragma unroll
            for (int nt = 0; nt < 4; nt++) accCn[i3][nt] = (f4){0.f, 0.f, 0.f, 0.f};
        for (int ic = 0; ic < 4; ic++) {
            pipe(16 + ic, wf);
            int u = 4 * ic + tl;
#pragma unroll
            for (int nt = 0; nt < 4; nt++)
#pragma unroll
                for (int i3 = 0; i3 < 3; i3++) {
                    float f = vT[i3][u][ebase + nt * 16 + el];
                    accCn[i3][nt] += f * wf[nt];
                }
        }
#pragma unroll
        for (int i3 = 0; i3 < 3; i3++)
#pragma unroll
            for (int nt = 0; nt < 4; nt++)
#pragma unroll
                for (int r = 0; r < 4; r++)
                    atomicAdd(&ovl.bc.bcC[i3][ebase + nt * 16 + el][q4 * 4 + r], accCn[i3][nt][r]);
    }

    // ---- A phase (i=20..83, g=i-20=u) then D phase (i=84..99, u=i-84); both -> acc0n
    f4 acc0n[4];
#pragma unroll
    for (int nt = 0; nt < 4; nt++) acc0n[nt] = (f4){0.f, 0.f, 0.f, 0.f};
    for (int ia = 0; ia < 64; ia++) {
        pipe(20 + ia, wf);
#pragma unroll
        for (int nt = 0; nt < 4; nt++) {
            float f = sh0n4[nt] * sT[ia][ebase + nt * 16 + el];
            acc0n[nt] += f * wf[nt];
        }
    }
    for (int id = 0; id < 15; id++) {
        pipe(84 + id, wf);
#pragma unroll
        for (int nt = 0; nt < 4; nt++) {
            float f = pT[id][ebase + nt * 16 + el];
            acc0n[nt] += f * wf[nt];
        }
    }
    // peeled last step i=99: only its own 3 ops outstanding -> vmcnt(0)
    {
        SB0();
        asm volatile("s_waitcnt vmcnt(0)" ::: "memory");
        __builtin_amdgcn_s_barrier();
        SB0();
        consume(99, wf);
#pragma unroll
        for (int nt = 0; nt < 4; nt++) {
            float f = pT[15][ebase + nt * 16 + el];
            acc0n[nt] += f * wf[nt];
        }
    }

    __syncthreads();   // loop reads of sT/vT/pT done; all bc atomics landed

    // out0 -> FLAT sT region [e*64 + c]; each (e,c) written by exactly one wave
    {
        float* out0 = (float*)sT;
#pragma unroll
        for (int nt = 0; nt < 4; nt++)
#pragma unroll
            for (int r = 0; r < 4; r++)
                out0[(ebase + nt * 16 + el) * 64 + tl * 16 + q4 * 4 + r] = N0_CONST * acc0n[nt][r];
    }
    // out1 assembly from bc sums -> vflat [e*48 + w*3 + i]
    {
        float* vflat = (float*)vT;
        for (int idx = tid; idx < 6144; idx += 512) {
            int e = idx / 48;
            int rem = idx - e * 48;
            int w = rem / 3;
            int i3 = rem - w * 3;
            vflat[idx] = N0_CONST * (ovl.bc.bcB[e][w] * sh1_s[i3][e] + ovl.bc.bcC[i3][e][w] * sh0_s[e]);
        }
    }
    __syncthreads();

    // single coalesced 56KB store of tp[e0..e0+128)[0..112) — nontemporal
    {
        const float* out0 = (const float*)sT;
        const float* vflat = (const float*)vT;
        float* tpe = tp + (size_t)e0 * 112;
        for (int idx = tid; idx < 128 * 112; idx += 512) {
            int e = idx / 112;
            int c = idx - e * 112;
            float val = (c < 64) ? out0[e * 64 + c] : vflat[e * 48 + (c - 64)];
            __builtin_nontemporal_store(val, &tpe[idx]);
        }
    }
}

// Per-node segment mean over CSR edge list + residual. Block = node, thread = col.
__global__ __launch_bounds__(128) void k_red(const float* __restrict__ tp,
                                             const int* __restrict__ ptr,
                                             const int* __restrict__ eids,
                                             const float* __restrict__ node_attr,
                                             float* __restrict__ out) {
    int n = blockIdx.x;
    int c = threadIdx.x;
    if (c >= 112) return;
    int a = ptr[n], b = ptr[n + 1];
    float s = 0.f;
    for (int i = a; i < b; i++) {
        int e = eids[i];
        s += tp[(size_t)e * 112 + c];
    }
    float d = fmaxf((float)(b - a), 1.f);
    out[n * 112 + c] = s / d + node_attr[n * 112 + c];
}

extern "C" void kernel_launch(void* const* d_in, const int* in_sizes, int n_in,
                              void* d_out, int out_size, void* d_ws, size_t ws_size,
                              hipStream_t stream) {
    const float* node_attr  = (const float*)d_in[0];
    const int*   edge_index = (const int*)d_in[1];
    const float* edge_attr  = (const float*)d_in[2];
    const float* edge_sh    = (const float*)d_in[3];
    const float* W1         = (const float*)d_in[6];
    const float* b1         = (const float*)d_in[7];
    const float* W2         = (const float*)d_in[8];
    const float* b2         = (const float*)d_in[9];
    float* out = (float*)d_out;

    char* ws = (char*)d_ws;
    u16*   w2s    = (u16*)ws;                     // 6400*128*2  = 1,638,400
    u16*   w1t    = (u16*)(ws + 1638400);         // 128*128*2   =    32,768
    u16*   hgl    = (u16*)(ws + 1671168);         // 32768*128*2 = 8,388,608
    float* tp     = (float*)(ws + 10059776);      // 32768*112*4 = 14,680,064
    int*   deg    = (int*)(ws + 24739840);        // 4096*4
    int*   ptr    = (int*)(ws + 24756224);        // 4097*4
    int*   cursor = (int*)(ws + 24772624);        // 4096*4
    int*   eids   = (int*)(ws + 24789024);        // 32768*4

    hipMemsetAsync(deg, 0, 16384, stream);
    k_prep<<<544, 256, 0, stream>>>(W2, W1, edge_index, w2s, w1t, deg);
    k_scan<<<1, 64, 0, stream>>>(deg, ptr, cursor);
    k_h<<<512, 256, 0, stream>>>(edge_attr, w1t, b1, edge_index, cursor, eids, hgl);
    k_main<<<256, 512, 0, stream>>>(w2s, hgl, b2, node_attr, edge_index, edge_sh, tp);
    k_red<<<4096, 128, 0, stream>>>(tp, ptr, eids, node_attr, out);
}

// Round 10
// 221.805 us; speedup vs baseline: 1.0830x; 1.0830x over previous
//
#include <hip/hip_runtime.h>

typedef unsigned short u16;
typedef __bf16 bf8 __attribute__((ext_vector_type(8)));
typedef float f4 __attribute__((ext_vector_type(4)));

#define E_EDGES 32768
#define N_NODES 4096
// col layout of w (WNUM=6400): A[u<64][w<64] @0, B[u<64][w<16] @4096, C[u<16][w<16] @5120, D[u<16][w<64] @5376
// tile = 16 cols x 128 k = 4KB; group g covers tiles 4g..4g+3; A g<64, B 64..79, C 80..83, D 84..99
#define N0_CONST 0.1118033988749895f       // sqrt(1/80); also equals N1*INV_SQRT3
#define INV_SQRT3_CONST 0.5773502691896258f

__device__ __forceinline__ u16 f2bf(float f) {
    unsigned u = __float_as_uint(f);
    u += 0x7FFFu + ((u >> 16) & 1u);   // RNE
    return (u16)(u >> 16);
}

// Weight prep + src-degree histogram, one launch (unchanged, verified)
__global__ __launch_bounds__(256) void k_prep(const float* __restrict__ W2, const float* __restrict__ W1,
                                              const int* __restrict__ edge_index,
                                              u16* __restrict__ w2s, u16* __restrict__ w1t,
                                              int* __restrict__ deg) {
    int b = blockIdx.x;
    int tid = threadIdx.x;
    if (b < 400) {
        __shared__ float w2l[128][17];           // [k][c], +1 pad
        {
            int k = tid >> 1, c8 = (tid & 1) * 8;
            const float* src = W2 + (size_t)k * 6400 + b * 16 + c8;
            float tmpf[8];
#pragma unroll
            for (int j = 0; j < 8; j++) tmpf[j] = src[j];
#pragma unroll
            for (int j = 0; j < 8; j++) w2l[k][c8 + j] = tmpf[j];
        }
        __syncthreads();
        int ks = tid >> 6, l = tid & 63;
        int el = l & 15, q4 = l >> 4;
        u16 tmp[8];
#pragma unroll
        for (int j = 0; j < 8; j++)
            tmp[j] = f2bf(w2l[ks * 32 + q4 * 8 + j][el]);
        *(uint4*)(w2s + b * 2048 + ks * 512 + l * 8) = *(uint4*)tmp;
    } else if (b < 416) {
        int t = (b - 400) * 256 + tid;
#pragma unroll
        for (int i = 0; i < 4; i++) {
            int idx = t * 4 + i;                // idx = c*128 + k
            int c = idx >> 7, k = idx & 127;
            w1t[idx] = f2bf(W1[k * 128 + c]);
        }
    } else {
        int t = (b - 416) * 256 + tid;          // 128 blocks * 256 = 32768 = E
        atomicAdd(&deg[edge_index[t]], 1);
    }
}

// Exclusive scan of deg[4096] -> ptr[0..4096] and cursor copy. 1 block, 64 threads.
__global__ void k_scan(const int* __restrict__ deg, int* __restrict__ ptr, int* __restrict__ cursor) {
    int t = threadIdx.x;           // 0..63
    int base = t * 64;
    int s = 0;
    for (int i = 0; i < 64; i++) s += deg[base + i];
    int x = s;
#pragma unroll
    for (int d = 1; d < 64; d <<= 1) {
        int y = __shfl_up(x, d, 64);
        if (t >= d) x += y;
    }
    int run = x - s;               // exclusive prefix
    for (int i = 0; i < 64; i++) {
        ptr[base + i] = run;
        cursor[base + i] = run;
        run += deg[base + i];
    }
    if (t == 63) ptr[4096] = run;
}

// h = relu(edge_attr @ W1 + b1), stored bf16 [E][128]; also fills CSR edge-id list via cursor
__global__ __launch_bounds__(256) void k_h(const float* __restrict__ ea,
                                           const u16* __restrict__ w1t,
                                           const float* __restrict__ b1,
                                           const int* __restrict__ edge_index,
                                           int* __restrict__ cursor,
                                           int* __restrict__ eids,
                                           u16* __restrict__ h) {
    __shared__ alignas(16) u16 ea_s[64][128];
    int tid = threadIdx.x;
    int e0 = blockIdx.x * 64;
    if (tid < 64) {                // CSR fill for this block's 64 edges
        int ge = e0 + tid;
        int s = edge_index[ge];
        int pos = atomicAdd(&cursor[s], 1);
        eids[pos] = ge;
    }
    {
        int e = tid >> 2, q = tid & 3;
        const float4* src = (const float4*)(ea + (size_t)(e0 + e) * 128 + q * 32);
#pragma unroll
        for (int i = 0; i < 8; i++) {
            float4 f = src[i];
            int c = q * 32 + i * 4;
            ea_s[e][c + 0] = f2bf(f.x); ea_s[e][c + 1] = f2bf(f.y);
            ea_s[e][c + 2] = f2bf(f.z); ea_s[e][c + 3] = f2bf(f.w);
        }
    }
    __syncthreads();
    int lane = tid & 63, wave = tid >> 6;
    int el = lane & 15, q4 = lane >> 4;
    f4 acc[4][2];
#pragma unroll
    for (int m = 0; m < 4; m++)
#pragma unroll
        for (int nt = 0; nt < 2; nt++) acc[m][nt] = (f4){0.f, 0.f, 0.f, 0.f};
#pragma unroll
    for (int ks = 0; ks < 4; ks++) {
        bf8 a[4], b[2];
#pragma unroll
        for (int m = 0; m < 4; m++) a[m] = *(const bf8*)&ea_s[m * 16 + el][ks * 32 + q4 * 8];
#pragma unroll
        for (int nt = 0; nt < 2; nt++) {
            int n = wave * 32 + nt * 16 + el;
            b[nt] = *(const bf8*)(w1t + n * 128 + ks * 32 + q4 * 8);
        }
#pragma unroll
        for (int m = 0; m < 4; m++)
#pragma unroll
            for (int nt = 0; nt < 2; nt++)
                acc[m][nt] = __builtin_amdgcn_mfma_f32_16x16x32_bf16(a[m], b[nt], acc[m][nt], 0, 0, 0);
    }
#pragma unroll
    for (int m = 0; m < 4; m++)
#pragma unroll
        for (int nt = 0; nt < 2; nt++) {
            int n = wave * 32 + nt * 16 + el;
            float bias = b1[n];
#pragma unroll
            for (int r = 0; r < 4; r++) {
                int e = e0 + m * 16 + q4 * 4 + r;
                float v = fmaxf(acc[m][nt][r] + bias, 0.f);
                h[(size_t)e * 128 + n] = f2bf(v);
            }
        }
}

// Fused: w = h@W2+b2 tile-by-tile -> contraction -> tp[E][112].
// ROUND-10: 512 blocks x 64 edges x 8 waves, NO loop barriers (free-running waves: the two
// best results, 95/108us, both had none; round 9's barrier lockstep = 135us). Wave =
// (tile tl=w&3, edge-half eh=w>>2) runs round-8's VERIFIED lean loop (VGPR 64, nt=2) over its
// 32 edges. 4 waves/SIMD (2 blocks/CU) = 2x round-4's latency hiding at round-4's L2 traffic:
// the eh=0/1 waves load identical tile addresses ~in-sync -> duplicate is an L1 hit.
__global__ __launch_bounds__(512, 2) void k_main(const u16* __restrict__ w2s,
                                                 const u16* __restrict__ hgl,
                                                 const float* __restrict__ b2,
                                                 const float* __restrict__ node_attr,
                                                 const int* __restrict__ edge_index,
                                                 const float* __restrict__ edge_sh,
                                                 float* __restrict__ tp) {
    __shared__ alignas(16) union {
        u16 h[64][136];                               // 17408 B (prologue; +8 pad)
        struct { float bcB[64][17]; float bcC[3][64][17]; } bc;   // 17408 B (B/C cross-wave sums)
    } ovl;
    __shared__ float sT[64][66];              // s[u][e]; epilogue: out0 FLAT [e*64+c] (4096<=4224)
    __shared__ float vT[3][16][66];           // v[i][u][e]; epilogue: vflat [e*48+cr] (3072<=3168)
    __shared__ float pT[16][66];              // INV_SQRT3*(v.sh1)[u][e]
    __shared__ float sh0_s[64];
    __shared__ float sh1_s[3][64];
    __shared__ int dst_s[64];

    int tid = threadIdx.x;
    int e0 = blockIdx.x * 64;
    int lane = tid & 63, wave = tid >> 6;     // wave 0..7
    int tl = wave & 3, eh = wave >> 2;        // tile-in-group / edge-half
    int el = lane & 15, q4 = lane >> 4;
    int ebase = eh * 32;                      // this wave's 32 edges: ebase..ebase+31

    // A-fragment double buffer (full K: 4 bf8) + per-tile bias (round-8 verified)
    bf8 a0[4], a1[4];
    float4 bb0, bb1;
    auto loadA = [&](int i, bf8 (&a)[4], float4& bb) {
        int g = (i < 20) ? 64 + i : (i < 84 ? i - 20 : i);   // phase order B,C,A,D
        int pn = 4 * g + tl;
        const u16* gp = w2s + (size_t)pn * 2048 + lane * 8;
        a[0] = *(const bf8*)(gp);
        a[1] = *(const bf8*)(gp + 512);
        a[2] = *(const bf8*)(gp + 1024);
        a[3] = *(const bf8*)(gp + 1536);
        bb = *(const float4*)(b2 + pn * 16 + q4 * 4);
    };
    loadA(0, a0, bb0);   // prefetch first tile under the whole prologue

    // phase 1: edge meta
    if (tid < 64) {
        int ge = e0 + tid;
        dst_s[tid] = edge_index[E_EDGES + ge];
        float4 sh = *(const float4*)(edge_sh + (size_t)ge * 4);
        sh0_s[tid] = sh.x; sh1_s[0][tid] = sh.y; sh1_s[1][tid] = sh.z; sh1_s[2][tid] = sh.w;
    }
    __syncthreads();

    // phase 2: 8 threads/edge: q<4 -> node features (transposed), q>=4 -> h tile copy
    {
        int e = tid >> 3, q = tid & 7;        // e 0..63
        if (q < 4) {
            int dst = dst_s[e];
            const float* xp = node_attr + (size_t)dst * 112;
#pragma unroll
            for (int i = 0; i < 4; i++) {
                float4 f = *(const float4*)(xp + q * 16 + i * 4);
                int u = q * 16 + i * 4;
                sT[u + 0][e] = f.x; sT[u + 1][e] = f.y; sT[u + 2][e] = f.z; sT[u + 3][e] = f.w;
            }
            float vv[12];
#pragma unroll
            for (int i = 0; i < 3; i++) {
                float4 f = *(const float4*)(xp + 64 + q * 12 + i * 4);
                vv[i * 4 + 0] = f.x; vv[i * 4 + 1] = f.y; vv[i * 4 + 2] = f.z; vv[i * 4 + 3] = f.w;
            }
            float s1x = sh1_s[0][e], s1y = sh1_s[1][e], s1z = sh1_s[2][e];
#pragma unroll
            for (int u = 0; u < 4; u++) {
                float xa = vv[u * 3 + 0], xb = vv[u * 3 + 1], xc = vv[u * 3 + 2];
                int uu = q * 4 + u;
                vT[0][uu][e] = xa; vT[1][uu][e] = xb; vT[2][uu][e] = xc;
                pT[uu][e] = INV_SQRT3_CONST * (xa * s1x + xb * s1y + xc * s1z);
            }
        } else {
            int qq = q - 4;
            const uint4* hsrc = (const uint4*)(hgl + (size_t)(e0 + e) * 128) + qq * 4;
            uint4* hdst = (uint4*)(&ovl.h[e][qq * 32]);
#pragma unroll
            for (int i = 0; i < 4; i++) hdst[i] = hsrc[i];
        }
    }
    __syncthreads();

    // h B-fragments for this wave's 2 edge-groups (32 VGPRs)
    bf8 hbf[2][4];
#pragma unroll
    for (int nt = 0; nt < 2; nt++)
#pragma unroll
        for (int ks = 0; ks < 4; ks++)
            hbf[nt][ks] = *(const bf8*)&ovl.h[ebase + nt * 16 + el][ks * 32 + q4 * 8];
    float sh0n2[2];
#pragma unroll
    for (int nt = 0; nt < 2; nt++) sh0n2[nt] = sh0_s[ebase + nt * 16 + el];
    __syncthreads();   // everyone done reading ovl.h -> becomes bc scratch

    // zero bc scratch (17408B = 4352 floats)
    for (int idx = tid; idx < 4352; idx += 512) ((float*)&ovl.bc)[idx] = 0.f;
    __syncthreads();   // bc zeroed before any wave's atomics

    auto mfmaG = [&](const bf8 (&a)[4], const float4& bb, f4 (&wf)[2]) {
#pragma unroll
        for (int nt = 0; nt < 2; nt++) wf[nt] = (f4){bb.x, bb.y, bb.z, bb.w};
#pragma unroll
        for (int ks = 0; ks < 4; ks++)
#pragma unroll
            for (int nt = 0; nt < 2; nt++)
                wf[nt] = __builtin_amdgcn_mfma_f32_16x16x32_bf16(a[ks], hbf[nt][ks], wf[nt], 0, 0, 0);
    };
    // per lane: wf[nt][r] = w[edge = ebase+nt*16+el][col-in-tile = q4*4+r]

#define STEP(INXT, ACUR, BBCUR, ANXT, BBNXT, CON) \
    { if ((INXT) < 100) loadA((INXT), ANXT, BBNXT); mfmaG(ACUR, BBCUR, wf); CON; }

    f4 wf[2];

    // ---- B phase (i=0..15, g=64+i, u=4*i+tl; out col w = q4*4+r)
    {
        f4 accBn[2];
#pragma unroll
        for (int nt = 0; nt < 2; nt++) accBn[nt] = (f4){0.f, 0.f, 0.f, 0.f};
        auto conB = [&](int ib) {
            int u = 4 * ib + tl;
#pragma unroll
            for (int nt = 0; nt < 2; nt++) {
                float f = sT[u][ebase + nt * 16 + el];
                accBn[nt] += f * wf[nt];
            }
        };
        for (int ii = 0; ii < 16; ii += 2) {
            STEP(ii + 1, a0, bb0, a1, bb1, conB(ii));
            STEP(ii + 2, a1, bb1, a0, bb0, conB(ii + 1));
        }
#pragma unroll
        for (int nt = 0; nt < 2; nt++)
#pragma unroll
            for (int r = 0; r < 4; r++)
                atomicAdd(&ovl.bc.bcB[ebase + nt * 16 + el][q4 * 4 + r], accBn[nt][r]);
    }

    // ---- C phase (i=16..19, g=80+(i-16), u=4*(i-16)+tl)
    {
        f4 accCn[3][2];
#pragma unroll
        for (int i3 = 0; i3 < 3; i3++)
#pragma unroll
            for (int nt = 0; nt < 2; nt++) accCn[i3][nt] = (f4){0.f, 0.f, 0.f, 0.f};
        auto conC = [&](int ic) {
            int u = 4 * ic + tl;
#pragma unroll
            for (int nt = 0; nt < 2; nt++) {
#pragma unroll
                for (int i3 = 0; i3 < 3; i3++) {
                    float f = vT[i3][u][ebase + nt * 16 + el];
                    accCn[i3][nt] += f * wf[nt];
                }
            }
        };
        for (int ii = 0; ii < 4; ii += 2) {
            STEP(16 + ii + 1, a0, bb0, a1, bb1, conC(ii));
            STEP(16 + ii + 2, a1, bb1, a0, bb0, conC(ii + 1));
        }
#pragma unroll
        for (int i3 = 0; i3 < 3; i3++)
#pragma unroll
            for (int nt = 0; nt < 2; nt++)
#pragma unroll
                for (int r = 0; r < 4; r++)
                    atomicAdd(&ovl.bc.bcC[i3][ebase + nt * 16 + el][q4 * 4 + r], accCn[i3][nt][r]);
    }

    // ---- A phase (i=20..83, g=i-20=u) then D phase (i=84..99, u=i-84); both -> acc0n
    f4 acc0n[2];
#pragma unroll
    for (int nt = 0; nt < 2; nt++) acc0n[nt] = (f4){0.f, 0.f, 0.f, 0.f};
    {
        auto conA = [&](int ia) {
#pragma unroll
            for (int nt = 0; nt < 2; nt++) {
                float f = sh0n2[nt] * sT[ia][ebase + nt * 16 + el];
                acc0n[nt] += f * wf[nt];
            }
        };
        for (int ii = 0; ii < 64; ii += 2) {
            STEP(20 + ii + 1, a0, bb0, a1, bb1, conA(ii));
            STEP(20 + ii + 2, a1, bb1, a0, bb0, conA(ii + 1));
        }
        auto conD = [&](int id_) {
#pragma unroll
            for (int nt = 0; nt < 2; nt++) {
                float f = pT[id_][ebase + nt * 16 + el];
                acc0n[nt] += f * wf[nt];
            }
        };
        for (int ii = 0; ii < 16; ii += 2) {
            STEP(84 + ii + 1, a0, bb0, a1, bb1, conD(ii));
            STEP(84 + ii + 2, a1, bb1, a0, bb0, conD(ii + 1));
        }
    }
#undef STEP

    __syncthreads();   // loop reads of sT/vT/pT done; all bc atomics landed

    // out0 -> FLAT sT region [e*64 + c]; each (e,c) written by exactly one wave
    {
        float* out0 = (float*)sT;
#pragma unroll
        for (int nt = 0; nt < 2; nt++)
#pragma unroll
            for (int r = 0; r < 4; r++)
                out0[(ebase + nt * 16 + el) * 64 + tl * 16 + q4 * 4 + r] = N0_CONST * acc0n[nt][r];
    }
    // out1 assembly from bc sums -> vflat [e*48 + w*3 + i]
    {
        float* vflat = (float*)vT;
        for (int idx = tid; idx < 3072; idx += 512) {
            int e = idx / 48;
            int rem = idx - e * 48;
            int w = rem / 3;
            int i3 = rem - w * 3;
            vflat[idx] = N0_CONST * (ovl.bc.bcB[e][w] * sh1_s[i3][e] + ovl.bc.bcC[i3][e][w] * sh0_s[e]);
        }
    }
    __syncthreads();

    // single coalesced 28KB store of tp[e0..e0+64)[0..112) — nontemporal
    {
        const float* out0 = (const float*)sT;
        const float* vflat = (const float*)vT;
        float* tpe = tp + (size_t)e0 * 112;
        for (int idx = tid; idx < 64 * 112; idx += 512) {
            int e = idx / 112;
            int c = idx - e * 112;
            float val = (c < 64) ? out0[e * 64 + c] : vflat[e * 48 + (c - 64)];
            __builtin_nontemporal_store(val, &tpe[idx]);
        }
    }
}

// Per-node segment mean over CSR edge list + residual. Block = node, thread = col.
__global__ __launch_bounds__(128) void k_red(const float* __restrict__ tp,
                                             const int* __restrict__ ptr,
                                             const int* __restrict__ eids,
                                             const float* __restrict__ node_attr,
                                             float* __restrict__ out) {
    int n = blockIdx.x;
    int c = threadIdx.x;
    if (c >= 112) return;
    int a = ptr[n], b = ptr[n + 1];
    float s = 0.f;
    for (int i = a; i < b; i++) {
        int e = eids[i];
        s += tp[(size_t)e * 112 + c];
    }
    float d = fmaxf((float)(b - a), 1.f);
    out[n * 112 + c] = s / d + node_attr[n * 112 + c];
}

extern "C" void kernel_launch(void* const* d_in, const int* in_sizes, int n_in,
                              void* d_out, int out_size, void* d_ws, size_t ws_size,
                              hipStream_t stream) {
    const float* node_attr  = (const float*)d_in[0];
    const int*   edge_index = (const int*)d_in[1];
    const float* edge_attr  = (const float*)d_in[2];
    const float* edge_sh    = (const float*)d_in[3];
    const float* W1         = (const float*)d_in[6];
    const float* b1         = (const float*)d_in[7];
    const float* W2         = (const float*)d_in[8];
    const float* b2         = (const float*)d_in[9];
    float* out = (float*)d_out;

    char* ws = (char*)d_ws;
    u16*   w2s    = (u16*)ws;                     // 6400*128*2  = 1,638,400
    u16*   w1t    = (u16*)(ws + 1638400);         // 128*128*2   =    32,768
    u16*   hgl    = (u16*)(ws + 1671168);         // 32768*128*2 = 8,388,608
    float* tp     = (float*)(ws + 10059776);      // 32768*112*4 = 14,680,064
    int*   deg    = (int*)(ws + 24739840);        // 4096*4
    int*   ptr    = (int*)(ws + 24756224);        // 4097*4
    int*   cursor = (int*)(ws + 24772624);        // 4096*4
    int*   eids   = (int*)(ws + 24789024);        // 32768*4

    hipMemsetAsync(deg, 0, 16384, stream);
    k_prep<<<544, 256, 0, stream>>>(W2, W1, edge_index, w2s, w1t, deg);
    k_scan<<<1, 64, 0, stream>>>(deg, ptr, cursor);
    k_h<<<512, 256, 0, stream>>>(edge_attr, w1t, b1, edge_index, cursor, eids, hgl);
    k_main<<<512, 512, 0, stream>>>(w2s, hgl, b2, node_attr, edge_index, edge_sh, tp);
    k_red<<<4096, 128, 0, stream>>>(tp, ptr, eids, node_attr, out);
}

// Round 11
// 189.499 us; speedup vs baseline: 1.2677x; 1.1705x over previous
//
#include <hip/hip_runtime.h>

typedef unsigned short u16;
typedef __bf16 bf8 __attribute__((ext_vector_type(8)));
typedef float f4 __attribute__((ext_vector_type(4)));

#define E_EDGES 32768
#define N_NODES 4096
// col layout of w (WNUM=6400): A[u<64][w<64] @0, B[u<64][w<16] @4096, C[u<16][w<16] @5120, D[u<16][w<64] @5376
// tile = 16 cols x 128 k = 4KB; group g covers tiles 4g..4g+3; A g<64, B 64..79, C 80..83, D 84..99
#define N0_CONST 0.1118033988749895f       // sqrt(1/80); also equals N1*INV_SQRT3
#define INV_SQRT3_CONST 0.5773502691896258f

__device__ __forceinline__ u16 f2bf(float f) {
    unsigned u = __float_as_uint(f);
    u += 0x7FFFu + ((u >> 16) & 1u);   // RNE
    return (u16)(u >> 16);
}

// Weight prep + src-degree histogram, one launch (verified):
//  blocks 0..399:   w2s fragment-order swizzle (tile = 4KB contiguous), via LDS re-stage
//  blocks 400..415: w1t[c*128+k] = bf16(W1[k*128+c])
//  blocks 416..543: deg histogram over edge src (deg pre-zeroed by memsetAsync)
__global__ __launch_bounds__(256) void k_prep(const float* __restrict__ W2, const float* __restrict__ W1,
                                              const int* __restrict__ edge_index,
                                              u16* __restrict__ w2s, u16* __restrict__ w1t,
                                              int* __restrict__ deg) {
    int b = blockIdx.x;
    int tid = threadIdx.x;
    if (b < 400) {
        __shared__ float w2l[128][17];           // [k][c], +1 pad
        {
            int k = tid >> 1, c8 = (tid & 1) * 8;
            const float* src = W2 + (size_t)k * 6400 + b * 16 + c8;
            float tmpf[8];
#pragma unroll
            for (int j = 0; j < 8; j++) tmpf[j] = src[j];
#pragma unroll
            for (int j = 0; j < 8; j++) w2l[k][c8 + j] = tmpf[j];
        }
        __syncthreads();
        int ks = tid >> 6, l = tid & 63;
        int el = l & 15, q4 = l >> 4;
        u16 tmp[8];
#pragma unroll
        for (int j = 0; j < 8; j++)
            tmp[j] = f2bf(w2l[ks * 32 + q4 * 8 + j][el]);
        *(uint4*)(w2s + b * 2048 + ks * 512 + l * 8) = *(uint4*)tmp;
    } else if (b < 416) {
        int t = (b - 400) * 256 + tid;
#pragma unroll
        for (int i = 0; i < 4; i++) {
            int idx = t * 4 + i;                // idx = c*128 + k
            int c = idx >> 7, k = idx & 127;
            w1t[idx] = f2bf(W1[k * 128 + c]);
        }
    } else {
        int t = (b - 416) * 256 + tid;          // 128 blocks * 256 = 32768 = E
        atomicAdd(&deg[edge_index[t]], 1);
    }
}

// h = relu(edge_attr @ W1 + b1), stored bf16 [E][128]. (CSR fill removed — no CSR anymore.)
__global__ __launch_bounds__(256) void k_h(const float* __restrict__ ea,
                                           const u16* __restrict__ w1t,
                                           const float* __restrict__ b1,
                                           u16* __restrict__ h) {
    __shared__ alignas(16) u16 ea_s[64][128];
    int tid = threadIdx.x;
    int e0 = blockIdx.x * 64;
    {
        int e = tid >> 2, q = tid & 3;
        const float4* src = (const float4*)(ea + (size_t)(e0 + e) * 128 + q * 32);
#pragma unroll
        for (int i = 0; i < 8; i++) {
            float4 f = src[i];
            int c = q * 32 + i * 4;
            ea_s[e][c + 0] = f2bf(f.x); ea_s[e][c + 1] = f2bf(f.y);
            ea_s[e][c + 2] = f2bf(f.z); ea_s[e][c + 3] = f2bf(f.w);
        }
    }
    __syncthreads();
    int lane = tid & 63, wave = tid >> 6;
    int el = lane & 15, q4 = lane >> 4;
    f4 acc[4][2];
#pragma unroll
    for (int m = 0; m < 4; m++)
#pragma unroll
        for (int nt = 0; nt < 2; nt++) acc[m][nt] = (f4){0.f, 0.f, 0.f, 0.f};
#pragma unroll
    for (int ks = 0; ks < 4; ks++) {
        bf8 a[4], b[2];
#pragma unroll
        for (int m = 0; m < 4; m++) a[m] = *(const bf8*)&ea_s[m * 16 + el][ks * 32 + q4 * 8];
#pragma unroll
        for (int nt = 0; nt < 2; nt++) {
            int n = wave * 32 + nt * 16 + el;
            b[nt] = *(const bf8*)(w1t + n * 128 + ks * 32 + q4 * 8);
        }
#pragma unroll
        for (int m = 0; m < 4; m++)
#pragma unroll
            for (int nt = 0; nt < 2; nt++)
                acc[m][nt] = __builtin_amdgcn_mfma_f32_16x16x32_bf16(a[m], b[nt], acc[m][nt], 0, 0, 0);
    }
#pragma unroll
    for (int m = 0; m < 4; m++)
#pragma unroll
        for (int nt = 0; nt < 2; nt++) {
            int n = wave * 32 + nt * 16 + el;
            float bias = b1[n];
#pragma unroll
            for (int r = 0; r < 4; r++) {
                int e = e0 + m * 16 + q4 * 4 + r;
                float v = fmaxf(acc[m][nt][r] + bias, 0.f);
                h[(size_t)e * 128 + n] = f2bf(v);
            }
        }
}

// Fused: w = h@W2+b2 tile-by-tile -> contraction -> ATOMIC scatter to out[src].
// Loop = round-4 VERBATIM (best verified config: 95us, 256thr/4 waves, 2 blk/CU, free-running,
// VGPR 100, zero spill). Changes vs round 4: phase 1 also loads src; epilogue atomicAdds the
// staged 64x112 tile into out[src*112+c] (replaces tp store; kills CSR + k_red + 29MB traffic).
__global__ __launch_bounds__(256, 2) void k_main(const u16* __restrict__ w2s,
                                                 const u16* __restrict__ hgl,
                                                 const float* __restrict__ b2,
                                                 const float* __restrict__ node_attr,
                                                 const int* __restrict__ edge_index,
                                                 const float* __restrict__ edge_sh,
                                                 float* __restrict__ outsum) {
    __shared__ alignas(16) union {
        u16 h[64][136];                               // 17408 B (prologue; +8 pad)
        struct { float bcB[64][17]; float bcC[3][64][17]; } bc;   // 17408 B (B/C cross-wave sums)
    } ovl;
    __shared__ float sT[64][66];              // s[u][e]; epilogue: out0[e][c] (c<64<=66, verified r4)
    __shared__ float vT[3][16][66];           // v[i][u][e]; epilogue: out1 flat [e*48+cr]
    __shared__ float pT[16][66];              // INV_SQRT3*(v.sh1)[u][e]
    __shared__ float sh0_s[64];
    __shared__ float sh1_s[3][64];
    __shared__ int dst_s[64];
    __shared__ int src_s[64];

    int tid = threadIdx.x;
    int e0 = blockIdx.x * 64;
    int lane = tid & 63, wave = tid >> 6;
    int el = lane & 15, q4 = lane >> 4;

    // A-fragment double buffer + per-tile bias; issued earliest for latency
    bf8 a0[4], a1[4];
    float4 bb0, bb1;
    auto loadA = [&](int i, bf8 (&a)[4], float4& bb) {
        int g = (i < 20) ? 64 + i : (i < 84 ? i - 20 : i);   // phase order B,C,A,D
        int pn = 4 * g + wave;
        const u16* gp = w2s + (size_t)pn * 2048 + lane * 8;
        a[0] = *(const bf8*)(gp);
        a[1] = *(const bf8*)(gp + 512);
        a[2] = *(const bf8*)(gp + 1024);
        a[3] = *(const bf8*)(gp + 1536);
        bb = *(const float4*)(b2 + pn * 16 + q4 * 4);
    };
    loadA(0, a0, bb0);   // prefetch first tile under the whole prologue

    // phase 1: edge meta (now also src for the scatter)
    if (tid < 64) {
        int ge = e0 + tid;
        src_s[tid] = edge_index[ge];
        dst_s[tid] = edge_index[E_EDGES + ge];
        float4 sh = *(const float4*)(edge_sh + (size_t)ge * 4);
        sh0_s[tid] = sh.x; sh1_s[0][tid] = sh.y; sh1_s[1][tid] = sh.z; sh1_s[2][tid] = sh.w;
    }
    __syncthreads();

    // phase 2: node features (transposed into LDS) + h tile into ovl.h
    {
        int e = tid >> 2, q = tid & 3;
        int dst = dst_s[e];
        const float* xp = node_attr + (size_t)dst * 112;
#pragma unroll
        for (int i = 0; i < 4; i++) {
            float4 f = *(const float4*)(xp + q * 16 + i * 4);
            int u = q * 16 + i * 4;
            sT[u + 0][e] = f.x; sT[u + 1][e] = f.y; sT[u + 2][e] = f.z; sT[u + 3][e] = f.w;
        }
        float vv[12];
#pragma unroll
        for (int i = 0; i < 3; i++) {
            float4 f = *(const float4*)(xp + 64 + q * 12 + i * 4);
            vv[i * 4 + 0] = f.x; vv[i * 4 + 1] = f.y; vv[i * 4 + 2] = f.z; vv[i * 4 + 3] = f.w;
        }
        float s1x = sh1_s[0][e], s1y = sh1_s[1][e], s1z = sh1_s[2][e];
#pragma unroll
        for (int u = 0; u < 4; u++) {
            float xa = vv[u * 3 + 0], xb = vv[u * 3 + 1], xc = vv[u * 3 + 2];
            int uu = q * 4 + u;
            vT[0][uu][e] = xa; vT[1][uu][e] = xb; vT[2][uu][e] = xc;
            pT[uu][e] = INV_SQRT3_CONST * (xa * s1x + xb * s1y + xc * s1z);
        }
        const uint4* hsrc = (const uint4*)(hgl + (size_t)(e0 + e) * 128) + q * 4;
        uint4* hdst = (uint4*)(&ovl.h[e][q * 32]);
#pragma unroll
        for (int i = 0; i < 4; i++) hdst[i] = hsrc[i];
    }
    __syncthreads();

    // h B-fragments for ALL 4 edge-groups (64 VGPRs) + per-lane sh0 factors
    bf8 hbf[4][4];
#pragma unroll
    for (int nt = 0; nt < 4; nt++)
#pragma unroll
        for (int ks = 0; ks < 4; ks++)
            hbf[nt][ks] = *(const bf8*)&ovl.h[nt * 16 + el][ks * 32 + q4 * 8];
    float sh0n4[4];
#pragma unroll
    for (int nt = 0; nt < 4; nt++) sh0n4[nt] = sh0_s[nt * 16 + el];
    __syncthreads();   // everyone done reading ovl.h -> becomes bc scratch

    // zero bc scratch (17408B = 4352 floats)
    for (int idx = tid; idx < 4352; idx += 256) ((float*)&ovl.bc)[idx] = 0.f;
    __syncthreads();   // bc zeroed before any wave's atomics

    auto mfmaG = [&](const bf8 (&a)[4], const float4& bb, f4 (&wf)[4]) {
#pragma unroll
        for (int nt = 0; nt < 4; nt++) wf[nt] = (f4){bb.x, bb.y, bb.z, bb.w};
#pragma unroll
        for (int ks = 0; ks < 4; ks++)
#pragma unroll
            for (int nt = 0; nt < 4; nt++)
                wf[nt] = __builtin_amdgcn_mfma_f32_16x16x32_bf16(a[ks], hbf[nt][ks], wf[nt], 0, 0, 0);
    };
    // result layout per lane: wf[nt][r] = w[edge = nt*16+el][col-in-tile = q4*4+r]

#define STEP(INXT, ACUR, BBCUR, ANXT, BBNXT, CON) \
    { if ((INXT) < 100) loadA((INXT), ANXT, BBNXT); mfmaG(ACUR, BBCUR, wf); CON; }

    f4 wf[4];

    // ---- B phase (i=0..15, g=64+i, u=4*i+wave; out col w = q4*4+r)
    {
        f4 accBn[4];
#pragma unroll
        for (int nt = 0; nt < 4; nt++) accBn[nt] = (f4){0.f, 0.f, 0.f, 0.f};
        auto conB = [&](int ib) {
            int u = 4 * ib + wave;
#pragma unroll
            for (int nt = 0; nt < 4; nt++) {
                float f = sT[u][nt * 16 + el];
                accBn[nt] += f * wf[nt];
            }
        };
        for (int ii = 0; ii < 16; ii += 2) {
            STEP(ii + 1, a0, bb0, a1, bb1, conB(ii));
            STEP(ii + 2, a1, bb1, a0, bb0, conB(ii + 1));
        }
#pragma unroll
        for (int nt = 0; nt < 4; nt++)
#pragma unroll
            for (int r = 0; r < 4; r++)
                atomicAdd(&ovl.bc.bcB[nt * 16 + el][q4 * 4 + r], accBn[nt][r]);
    }

    // ---- C phase (i=16..19, g=80+(i-16), u=4*(i-16)+wave)
    {
        f4 accCn[3][4];
#pragma unroll
        for (int i3 = 0; i3 < 3; i3++)
#pragma unroll
            for (int nt = 0; nt < 4; nt++) accCn[i3][nt] = (f4){0.f, 0.f, 0.f, 0.f};
        auto conC = [&](int ic) {
            int u = 4 * ic + wave;
#pragma unroll
            for (int nt = 0; nt < 4; nt++) {
#pragma unroll
                for (int i3 = 0; i3 < 3; i3++) {
                    float f = vT[i3][u][nt * 16 + el];
                    accCn[i3][nt] += f * wf[nt];
                }
            }
        };
        for (int ii = 0; ii < 4; ii += 2) {
            STEP(16 + ii + 1, a0, bb0, a1, bb1, conC(ii));
            STEP(16 + ii + 2, a1, bb1, a0, bb0, conC(ii + 1));
        }
#pragma unroll
        for (int i3 = 0; i3 < 3; i3++)
#pragma unroll
            for (int nt = 0; nt < 4; nt++)
#pragma unroll
                for (int r = 0; r < 4; r++)
                    atomicAdd(&ovl.bc.bcC[i3][nt * 16 + el][q4 * 4 + r], accCn[i3][nt][r]);
    }

    // ---- A phase (i=20..83, g=i-20=u) then D phase (i=84..99, u=i-84); both -> acc0n
    f4 acc0n[4];
#pragma unroll
    for (int nt = 0; nt < 4; nt++) acc0n[nt] = (f4){0.f, 0.f, 0.f, 0.f};
    {
        auto conA = [&](int ia) {
#pragma unroll
            for (int nt = 0; nt < 4; nt++) {
                float f = sh0n4[nt] * sT[ia][nt * 16 + el];
                acc0n[nt] += f * wf[nt];
            }
        };
        for (int ii = 0; ii < 64; ii += 2) {
            STEP(20 + ii + 1, a0, bb0, a1, bb1, conA(ii));
            STEP(20 + ii + 2, a1, bb1, a0, bb0, conA(ii + 1));
        }
        auto conD = [&](int id_) {
#pragma unroll
            for (int nt = 0; nt < 4; nt++) {
                float f = pT[id_][nt * 16 + el];
                acc0n[nt] += f * wf[nt];
            }
        };
        for (int ii = 0; ii < 16; ii += 2) {
            STEP(84 + ii + 1, a0, bb0, a1, bb1, conD(ii));
            STEP(84 + ii + 2, a1, bb1, a0, bb0, conD(ii + 1));
        }
    }
#undef STEP

    __syncthreads();   // loop reads of sT/vT/pT done; all bc atomics landed

    // out0 -> sT[e][c]: wave owns col block wave*16 (A/D cols), all 64 edges
#pragma unroll
    for (int nt = 0; nt < 4; nt++)
#pragma unroll
        for (int r = 0; r < 4; r++)
            sT[nt * 16 + el][wave * 16 + q4 * 4 + r] = N0_CONST * acc0n[nt][r];
    // out1 assembly from bc sums -> vflat [e*48 + w*3 + i]
    {
        float* vflat = (float*)vT;
        for (int idx = tid; idx < 3072; idx += 256) {
            int e = idx / 48;
            int rem = idx - e * 48;
            int w = rem / 3;
            int i3 = rem - w * 3;
            vflat[idx] = N0_CONST * (ovl.bc.bcB[e][w] * sh1_s[i3][e] + ovl.bc.bcC[i3][e][w] * sh0_s[e]);
        }
    }
    __syncthreads();

    // ATOMIC scatter of the 64x112 tile into out[src*112 + c] (device-scope, L2-resident 1.8MB)
    {
        const float* vflat = (const float*)vT;
        for (int idx = tid; idx < 64 * 112; idx += 256) {
            int e = idx / 112;
            int c = idx - e * 112;
            float val = (c < 64) ? sT[e][c] : vflat[e * 48 + (c - 64)];
            atomicAdd(&outsum[(size_t)src_s[e] * 112 + c], val);
        }
    }
}

// Final: out = out_sum/max(deg,1) + node_attr. Block = node, thread = col.
__global__ __launch_bounds__(128) void k_fin(const int* __restrict__ deg,
                                             const float* __restrict__ node_attr,
                                             float* __restrict__ out) {
    int n = blockIdx.x;
    int c = threadIdx.x;
    if (c >= 112) return;
    float d = fmaxf((float)deg[n], 1.f);
    out[n * 112 + c] = out[n * 112 + c] / d + node_attr[n * 112 + c];
}

extern "C" void kernel_launch(void* const* d_in, const int* in_sizes, int n_in,
                              void* d_out, int out_size, void* d_ws, size_t ws_size,
                              hipStream_t stream) {
    const float* node_attr  = (const float*)d_in[0];
    const int*   edge_index = (const int*)d_in[1];
    const float* edge_attr  = (const float*)d_in[2];
    const float* edge_sh    = (const float*)d_in[3];
    const float* W1         = (const float*)d_in[6];
    const float* b1         = (const float*)d_in[7];
    const float* W2         = (const float*)d_in[8];
    const float* b2         = (const float*)d_in[9];
    float* out = (float*)d_out;

    char* ws = (char*)d_ws;
    u16*   w2s    = (u16*)ws;                     // 6400*128*2  = 1,638,400
    u16*   w1t    = (u16*)(ws + 1638400);         // 128*128*2   =    32,768
    u16*   hgl    = (u16*)(ws + 1671168);         // 32768*128*2 = 8,388,608
    int*   deg    = (int*)(ws + 10059776);        // 4096*4

    hipMemsetAsync(deg, 0, 16384, stream);
    hipMemsetAsync(out, 0, (size_t)N_NODES * 112 * 4, stream);
    k_prep<<<544, 256, 0, stream>>>(W2, W1, edge_index, w2s, w1t, deg);
    k_h<<<512, 256, 0, stream>>>(edge_attr, w1t, b1, hgl);
    k_main<<<512, 256, 0, stream>>>(w2s, hgl, b2, node_attr, edge_index, edge_sh, out);
    k_fin<<<4096, 128, 0, stream>>>(deg, node_attr, out);
}

// Round 12
// 185.305 us; speedup vs baseline: 1.2964x; 1.0226x over previous
//
#include <hip/hip_runtime.h>

typedef unsigned short u16;
typedef __bf16 bf8 __attribute__((ext_vector_type(8)));
typedef float f4 __attribute__((ext_vector_type(4)));

#define E_EDGES 32768
#define N_NODES 4096
// col layout of w (WNUM=6400): A[u<64][w<64] @0, B[u<64][w<16] @4096, C[u<16][w<16] @5120, D[u<16][w<64] @5376
// tile = 16 cols x 128 k = 4KB; group g covers tiles 4g..4g+3; A g<64, B 64..79, C 80..83, D 84..99
#define N0_CONST 0.1118033988749895f       // sqrt(1/80); also equals N1*INV_SQRT3
#define INV_SQRT3_CONST 0.5773502691896258f

__device__ __forceinline__ u16 f2bf(float f) {
    unsigned u = __float_as_uint(f);
    u += 0x7FFFu + ((u >> 16) & 1u);   // RNE
    return (u16)(u >> 16);
}

// Weight prep + src-degree histogram, one launch (verified):
//  blocks 0..399:   w2s fragment-order swizzle (tile = 4KB contiguous), via LDS re-stage
//  blocks 400..415: w1t[c*128+k] = bf16(W1[k*128+c])
//  blocks 416..543: deg histogram over edge src (deg pre-zeroed by memsetAsync)
__global__ __launch_bounds__(256) void k_prep(const float* __restrict__ W2, const float* __restrict__ W1,
                                              const int* __restrict__ edge_index,
                                              u16* __restrict__ w2s, u16* __restrict__ w1t,
                                              int* __restrict__ deg) {
    int b = blockIdx.x;
    int tid = threadIdx.x;
    if (b < 400) {
        __shared__ float w2l[128][17];           // [k][c], +1 pad
        {
            int k = tid >> 1, c8 = (tid & 1) * 8;
            const float* src = W2 + (size_t)k * 6400 + b * 16 + c8;
            float tmpf[8];
#pragma unroll
            for (int j = 0; j < 8; j++) tmpf[j] = src[j];
#pragma unroll
            for (int j = 0; j < 8; j++) w2l[k][c8 + j] = tmpf[j];
        }
        __syncthreads();
        int ks = tid >> 6, l = tid & 63;
        int el = l & 15, q4 = l >> 4;
        u16 tmp[8];
#pragma unroll
        for (int j = 0; j < 8; j++)
            tmp[j] = f2bf(w2l[ks * 32 + q4 * 8 + j][el]);
        *(uint4*)(w2s + b * 2048 + ks * 512 + l * 8) = *(uint4*)tmp;
    } else if (b < 416) {
        int t = (b - 400) * 256 + tid;
#pragma unroll
        for (int i = 0; i < 4; i++) {
            int idx = t * 4 + i;                // idx = c*128 + k
            int c = idx >> 7, k = idx & 127;
            w1t[idx] = f2bf(W1[k * 128 + c]);
        }
    } else {
        int t = (b - 416) * 256 + tid;          // 128 blocks * 256 = 32768 = E
        atomicAdd(&deg[edge_index[t]], 1);
    }
}

// Fused: h = relu(ea@W1+b1) in-prologue -> w = h@W2+b2 tile-by-tile -> contraction
// -> ATOMIC scatter to out[src].
// Loop = round-4/11 VERBATIM (verified: 95us loop, VGPR 100, zero spill, free-running waves).
// ROUND-12: k_h fused into the prologue — its block partition was identical (64 edges/block,
// 512 blocks) and h was consumed exactly once, here. Stage ea bf16 into ovl.h, run k_h's
// 16-MFMA block (B-frags from L2-resident w1t), write h back into ovl.h in place. Kills the
// k_h launch + 16.8MB of hgl HBM round-trip.
__global__ __launch_bounds__(256, 2) void k_main(const u16* __restrict__ w2s,
                                                 const u16* __restrict__ w1t,
                                                 const float* __restrict__ b1,
                                                 const float* __restrict__ ea,
                                                 const float* __restrict__ b2,
                                                 const float* __restrict__ node_attr,
                                                 const int* __restrict__ edge_index,
                                                 const float* __restrict__ edge_sh,
                                                 float* __restrict__ outsum) {
    __shared__ alignas(16) union {
        u16 h[64][136];                               // 17408 B (prologue: ea staging, then h; +8 pad)
        struct { float bcB[64][17]; float bcC[3][64][17]; } bc;   // 17408 B (B/C cross-wave sums)
    } ovl;
    __shared__ float sT[64][66];              // s[u][e]; epilogue: out0[e][c] (c<64<=66, verified r4)
    __shared__ float vT[3][16][66];           // v[i][u][e]; epilogue: out1 flat [e*48+cr]
    __shared__ float pT[16][66];              // INV_SQRT3*(v.sh1)[u][e]
    __shared__ float sh0_s[64];
    __shared__ float sh1_s[3][64];
    __shared__ int dst_s[64];
    __shared__ int src_s[64];

    int tid = threadIdx.x;
    int e0 = blockIdx.x * 64;
    int lane = tid & 63, wave = tid >> 6;
    int el = lane & 15, q4 = lane >> 4;

    // A-fragment double buffer + per-tile bias; issued earliest for latency
    bf8 a0[4], a1[4];
    float4 bb0, bb1;
    auto loadA = [&](int i, bf8 (&a)[4], float4& bb) {
        int g = (i < 20) ? 64 + i : (i < 84 ? i - 20 : i);   // phase order B,C,A,D
        int pn = 4 * g + wave;
        const u16* gp = w2s + (size_t)pn * 2048 + lane * 8;
        a[0] = *(const bf8*)(gp);
        a[1] = *(const bf8*)(gp + 512);
        a[2] = *(const bf8*)(gp + 1024);
        a[3] = *(const bf8*)(gp + 1536);
        bb = *(const float4*)(b2 + pn * 16 + q4 * 4);
    };
    loadA(0, a0, bb0);   // prefetch first tile under the whole prologue

    // phase 1: edge meta
    if (tid < 64) {
        int ge = e0 + tid;
        src_s[tid] = edge_index[ge];
        dst_s[tid] = edge_index[E_EDGES + ge];
        float4 sh = *(const float4*)(edge_sh + (size_t)ge * 4);
        sh0_s[tid] = sh.x; sh1_s[0][tid] = sh.y; sh1_s[1][tid] = sh.z; sh1_s[2][tid] = sh.w;
    }
    __syncthreads();

    // phase 2: node features (transposed into LDS) + ea tile bf16 into ovl.h
    {
        int e = tid >> 2, q = tid & 3;
        int dst = dst_s[e];
        const float* xp = node_attr + (size_t)dst * 112;
#pragma unroll
        for (int i = 0; i < 4; i++) {
            float4 f = *(const float4*)(xp + q * 16 + i * 4);
            int u = q * 16 + i * 4;
            sT[u + 0][e] = f.x; sT[u + 1][e] = f.y; sT[u + 2][e] = f.z; sT[u + 3][e] = f.w;
        }
        float vv[12];
#pragma unroll
        for (int i = 0; i < 3; i++) {
            float4 f = *(const float4*)(xp + 64 + q * 12 + i * 4);
            vv[i * 4 + 0] = f.x; vv[i * 4 + 1] = f.y; vv[i * 4 + 2] = f.z; vv[i * 4 + 3] = f.w;
        }
        float s1x = sh1_s[0][e], s1y = sh1_s[1][e], s1z = sh1_s[2][e];
#pragma unroll
        for (int u = 0; u < 4; u++) {
            float xa = vv[u * 3 + 0], xb = vv[u * 3 + 1], xc = vv[u * 3 + 2];
            int uu = q * 4 + u;
            vT[0][uu][e] = xa; vT[1][uu][e] = xb; vT[2][uu][e] = xc;
            pT[uu][e] = INV_SQRT3_CONST * (xa * s1x + xb * s1y + xc * s1z);
        }
        // ea staging (was k_h's): 32 cols per thread, f32 -> bf16
        const float4* src = (const float4*)(ea + (size_t)(e0 + e) * 128 + q * 32);
#pragma unroll
        for (int i = 0; i < 8; i++) {
            float4 f = src[i];
            int c = q * 32 + i * 4;
            ovl.h[e][c + 0] = f2bf(f.x); ovl.h[e][c + 1] = f2bf(f.y);
            ovl.h[e][c + 2] = f2bf(f.z); ovl.h[e][c + 3] = f2bf(f.w);
        }
    }
    __syncthreads();

    // phase 3: h = relu(ea@W1+b1) — k_h's MFMA block verbatim (ea read from ovl.h, stride 136)
    {
        f4 hacc[4][2];
#pragma unroll
        for (int m = 0; m < 4; m++)
#pragma unroll
            for (int nt = 0; nt < 2; nt++) hacc[m][nt] = (f4){0.f, 0.f, 0.f, 0.f};
#pragma unroll
        for (int ks = 0; ks < 4; ks++) {
            bf8 a[4], b[2];
#pragma unroll
            for (int m = 0; m < 4; m++) a[m] = *(const bf8*)&ovl.h[m * 16 + el][ks * 32 + q4 * 8];
#pragma unroll
            for (int nt = 0; nt < 2; nt++) {
                int n = wave * 32 + nt * 16 + el;
                b[nt] = *(const bf8*)(w1t + n * 128 + ks * 32 + q4 * 8);
            }
#pragma unroll
            for (int m = 0; m < 4; m++)
#pragma unroll
                for (int nt = 0; nt < 2; nt++)
                    hacc[m][nt] = __builtin_amdgcn_mfma_f32_16x16x32_bf16(a[m], b[nt], hacc[m][nt], 0, 0, 0);
        }
        __syncthreads();   // all ea reads done -> safe to overwrite ovl.h with h
#pragma unroll
        for (int m = 0; m < 4; m++)
#pragma unroll
            for (int nt = 0; nt < 2; nt++) {
                int n = wave * 32 + nt * 16 + el;
                float bias = b1[n];
#pragma unroll
                for (int r = 0; r < 4; r++) {
                    int e = m * 16 + q4 * 4 + r;
                    ovl.h[e][n] = f2bf(fmaxf(hacc[m][nt][r] + bias, 0.f));
                }
            }
    }
    __syncthreads();

    // h B-fragments for ALL 4 edge-groups (64 VGPRs) + per-lane sh0 factors
    bf8 hbf[4][4];
#pragma unroll
    for (int nt = 0; nt < 4; nt++)
#pragma unroll
        for (int ks = 0; ks < 4; ks++)
            hbf[nt][ks] = *(const bf8*)&ovl.h[nt * 16 + el][ks * 32 + q4 * 8];
    float sh0n4[4];
#pragma unroll
    for (int nt = 0; nt < 4; nt++) sh0n4[nt] = sh0_s[nt * 16 + el];
    __syncthreads();   // everyone done reading ovl.h -> becomes bc scratch

    // zero bc scratch (17408B = 4352 floats)
    for (int idx = tid; idx < 4352; idx += 256) ((float*)&ovl.bc)[idx] = 0.f;
    __syncthreads();   // bc zeroed before any wave's atomics

    auto mfmaG = [&](const bf8 (&a)[4], const float4& bb, f4 (&wf)[4]) {
#pragma unroll
        for (int nt = 0; nt < 4; nt++) wf[nt] = (f4){bb.x, bb.y, bb.z, bb.w};
#pragma unroll
        for (int ks = 0; ks < 4; ks++)
#pragma unroll
            for (int nt = 0; nt < 4; nt++)
                wf[nt] = __builtin_amdgcn_mfma_f32_16x16x32_bf16(a[ks], hbf[nt][ks], wf[nt], 0, 0, 0);
    };
    // result layout per lane: wf[nt][r] = w[edge = nt*16+el][col-in-tile = q4*4+r]

#define STEP(INXT, ACUR, BBCUR, ANXT, BBNXT, CON) \
    { if ((INXT) < 100) loadA((INXT), ANXT, BBNXT); mfmaG(ACUR, BBCUR, wf); CON; }

    f4 wf[4];

    // ---- B phase (i=0..15, g=64+i, u=4*i+wave; out col w = q4*4+r)
    {
        f4 accBn[4];
#pragma unroll
        for (int nt = 0; nt < 4; nt++) accBn[nt] = (f4){0.f, 0.f, 0.f, 0.f};
        auto conB = [&](int ib) {
            int u = 4 * ib + wave;
#pragma unroll
            for (int nt = 0; nt < 4; nt++) {
                float f = sT[u][nt * 16 + el];
                accBn[nt] += f * wf[nt];
            }
        };
        for (int ii = 0; ii < 16; ii += 2) {
            STEP(ii + 1, a0, bb0, a1, bb1, conB(ii));
            STEP(ii + 2, a1, bb1, a0, bb0, conB(ii + 1));
        }
#pragma unroll
        for (int nt = 0; nt < 4; nt++)
#pragma unroll
            for (int r = 0; r < 4; r++)
                atomicAdd(&ovl.bc.bcB[nt * 16 + el][q4 * 4 + r], accBn[nt][r]);
    }

    // ---- C phase (i=16..19, g=80+(i-16), u=4*(i-16)+wave)
    {
        f4 accCn[3][4];
#pragma unroll
        for (int i3 = 0; i3 < 3; i3++)
#pragma unroll
            for (int nt = 0; nt < 4; nt++) accCn[i3][nt] = (f4){0.f, 0.f, 0.f, 0.f};
        auto conC = [&](int ic) {
            int u = 4 * ic + wave;
#pragma unroll
            for (int nt = 0; nt < 4; nt++) {
#pragma unroll
                for (int i3 = 0; i3 < 3; i3++) {
                    float f = vT[i3][u][nt * 16 + el];
                    accCn[i3][nt] += f * wf[nt];
                }
            }
        };
        for (int ii = 0; ii < 4; ii += 2) {
            STEP(16 + ii + 1, a0, bb0, a1, bb1, conC(ii));
            STEP(16 + ii + 2, a1, bb1, a0, bb0, conC(ii + 1));
        }
#pragma unroll
        for (int i3 = 0; i3 < 3; i3++)
#pragma unroll
            for (int nt = 0; nt < 4; nt++)
#pragma unroll
                for (int r = 0; r < 4; r++)
                    atomicAdd(&ovl.bc.bcC[i3][nt * 16 + el][q4 * 4 + r], accCn[i3][nt][r]);
    }

    // ---- A phase (i=20..83, g=i-20=u) then D phase (i=84..99, u=i-84); both -> acc0n
    f4 acc0n[4];
#pragma unroll
    for (int nt = 0; nt < 4; nt++) acc0n[nt] = (f4){0.f, 0.f, 0.f, 0.f};
    {
        auto conA = [&](int ia) {
#pragma unroll
            for (int nt = 0; nt < 4; nt++) {
                float f = sh0n4[nt] * sT[ia][nt * 16 + el];
                acc0n[nt] += f * wf[nt];
            }
        };
        for (int ii = 0; ii < 64; ii += 2) {
            STEP(20 + ii + 1, a0, bb0, a1, bb1, conA(ii));
            STEP(20 + ii + 2, a1, bb1, a0, bb0, conA(ii + 1));
        }
        auto conD = [&](int id_) {
#pragma unroll
            for (int nt = 0; nt < 4; nt++) {
                float f = pT[id_][nt * 16 + el];
                acc0n[nt] += f * wf[nt];
            }
        };
        for (int ii = 0; ii < 16; ii += 2) {
            STEP(84 + ii + 1, a0, bb0, a1, bb1, conD(ii));
            STEP(84 + ii + 2, a1, bb1, a0, bb0, conD(ii + 1));
        }
    }
#undef STEP

    __syncthreads();   // loop reads of sT/vT/pT done; all bc atomics landed

    // out0 -> sT[e][c]: wave owns col block wave*16 (A/D cols), all 64 edges
#pragma unroll
    for (int nt = 0; nt < 4; nt++)
#pragma unroll
        for (int r = 0; r < 4; r++)
            sT[nt * 16 + el][wave * 16 + q4 * 4 + r] = N0_CONST * acc0n[nt][r];
    // out1 assembly from bc sums -> vflat [e*48 + w*3 + i]
    {
        float* vflat = (float*)vT;
        for (int idx = tid; idx < 3072; idx += 256) {
            int e = idx / 48;
            int rem = idx - e * 48;
            int w = rem / 3;
            int i3 = rem - w * 3;
            vflat[idx] = N0_CONST * (ovl.bc.bcB[e][w] * sh1_s[i3][e] + ovl.bc.bcC[i3][e][w] * sh0_s[e]);
        }
    }
    __syncthreads();

    // ATOMIC scatter of the 64x112 tile into out[src*112 + c] (device-scope, L2-resident 1.8MB)
    {
        const float* vflat = (const float*)vT;
        for (int idx = tid; idx < 64 * 112; idx += 256) {
            int e = idx / 112;
            int c = idx - e * 112;
            float val = (c < 64) ? sT[e][c] : vflat[e * 48 + (c - 64)];
            atomicAdd(&outsum[(size_t)src_s[e] * 112 + c], val);
        }
    }
}

// Final: out = out_sum/max(deg,1) + node_attr. Block = node, thread = col.
__global__ __launch_bounds__(128) void k_fin(const int* __restrict__ deg,
                                             const float* __restrict__ node_attr,
                                             float* __restrict__ out) {
    int n = blockIdx.x;
    int c = threadIdx.x;
    if (c >= 112) return;
    float d = fmaxf((float)deg[n], 1.f);
    out[n * 112 + c] = out[n * 112 + c] / d + node_attr[n * 112 + c];
}

extern "C" void kernel_launch(void* const* d_in, const int* in_sizes, int n_in,
                              void* d_out, int out_size, void* d_ws, size_t ws_size,
                              hipStream_t stream) {
    const float* node_attr  = (const float*)d_in[0];
    const int*   edge_index = (const int*)d_in[1];
    const float* edge_attr  = (const float*)d_in[2];
    const float* edge_sh    = (const float*)d_in[3];
    const float* W1         = (const float*)d_in[6];
    const float* b1         = (const float*)d_in[7];
    const float* W2         = (const float*)d_in[8];
    const float* b2         = (const float*)d_in[9];
    float* out = (float*)d_out;

    char* ws = (char*)d_ws;
    u16*   w2s    = (u16*)ws;                     // 6400*128*2  = 1,638,400
    u16*   w1t    = (u16*)(ws + 1638400);         // 128*128*2   =    32,768
    int*   deg    = (int*)(ws + 1671168);         // 4096*4

    hipMemsetAsync(deg, 0, 16384, stream);
    hipMemsetAsync(out, 0, (size_t)N_NODES * 112 * 4, stream);
    k_prep<<<544, 256, 0, stream>>>(W2, W1, edge_index, w2s, w1t, deg);
    k_main<<<512, 256, 0, stream>>>(w2s, w1t, b1, edge_attr, b2, node_attr, edge_index, edge_sh, out);
    k_fin<<<4096, 128, 0, stream>>>(deg, node_attr, out);
}

// Round 13
// 180.838 us; speedup vs baseline: 1.3284x; 1.0247x over previous
//
#include <hip/hip_runtime.h>

typedef unsigned short u16;
typedef __bf16 bf8 __attribute__((ext_vector_type(8)));
typedef float f4 __attribute__((ext_vector_type(4)));

#define E_EDGES 32768
#define N_NODES 4096
// col layout of w (WNUM=6400): A[u<64][w<64] @0, B[u<64][w<16] @4096, C[u<16][w<16] @5120, D[u<16][w<64] @5376
// tile = 16 cols x 128 k = 4KB; group g covers tiles 4g..4g+3; A g<64, B 64..79, C 80..83, D 84..99
#define N0_CONST 0.1118033988749895f       // sqrt(1/80); also equals N1*INV_SQRT3
#define INV_SQRT3_CONST 0.5773502691896258f

__device__ __forceinline__ u16 f2bf(float f) {
    unsigned u = __float_as_uint(f);
    u += 0x7FFFu + ((u >> 16) & 1u);   // RNE
    return (u16)(u >> 16);
}

// Weight prep + output/deg zero-fill, one launch (ROUND-13: absorbs both memsetAsync ops;
// deg histogram moved to k_main so deg-zero and histogram aren't in the same dispatch):
//  blocks 0..399:   w2s fragment-order swizzle (tile = 4KB contiguous), via LDS re-stage
//  blocks 400..415: w1t[c*128+k] = bf16(W1[k*128+c])
//  block  416:      zero deg[4096]
//  blocks 417..472: zero out[4096*112] (56*256*32 = 458752 floats exactly)
__global__ __launch_bounds__(256) void k_prep(const float* __restrict__ W2, const float* __restrict__ W1,
                                              u16* __restrict__ w2s, u16* __restrict__ w1t,
                                              int* __restrict__ deg, float* __restrict__ outz) {
    int b = blockIdx.x;
    int tid = threadIdx.x;
    if (b < 400) {
        __shared__ float w2l[128][17];           // [k][c], +1 pad
        {
            int k = tid >> 1, c8 = (tid & 1) * 8;
            const float* src = W2 + (size_t)k * 6400 + b * 16 + c8;
            float tmpf[8];
#pragma unroll
            for (int j = 0; j < 8; j++) tmpf[j] = src[j];
#pragma unroll
            for (int j = 0; j < 8; j++) w2l[k][c8 + j] = tmpf[j];
        }
        __syncthreads();
        int ks = tid >> 6, l = tid & 63;
        int el = l & 15, q4 = l >> 4;
        u16 tmp[8];
#pragma unroll
        for (int j = 0; j < 8; j++)
            tmp[j] = f2bf(w2l[ks * 32 + q4 * 8 + j][el]);
        *(uint4*)(w2s + b * 2048 + ks * 512 + l * 8) = *(uint4*)tmp;
    } else if (b < 416) {
        int t = (b - 400) * 256 + tid;
#pragma unroll
        for (int i = 0; i < 4; i++) {
            int idx = t * 4 + i;                // idx = c*128 + k
            int c = idx >> 7, k = idx & 127;
            w1t[idx] = f2bf(W1[k * 128 + c]);
        }
    } else if (b == 416) {
        *(int4*)&deg[tid * 16] = (int4){0, 0, 0, 0};
        *(int4*)&deg[tid * 16 + 4] = (int4){0, 0, 0, 0};
        *(int4*)&deg[tid * 16 + 8] = (int4){0, 0, 0, 0};
        *(int4*)&deg[tid * 16 + 12] = (int4){0, 0, 0, 0};
    } else {
        float4 z = {0.f, 0.f, 0.f, 0.f};
        float* p = outz + ((size_t)(b - 417) * 256 + tid) * 32;
#pragma unroll
        for (int i = 0; i < 8; i++) *(float4*)(p + i * 4) = z;
    }
}

// Fused: h = relu(ea@W1+b1) in-prologue -> w = h@W2+b2 tile-by-tile -> contraction
// -> ATOMIC scatter to out[src]. Also builds the deg histogram (phase 1).
// Loop = round-4/11/12 VERBATIM (verified: VGPR 96, zero spill, free-running waves).
__global__ __launch_bounds__(256, 2) void k_main(const u16* __restrict__ w2s,
                                                 const u16* __restrict__ w1t,
                                                 const float* __restrict__ b1,
                                                 const float* __restrict__ ea,
                                                 const float* __restrict__ b2,
                                                 const float* __restrict__ node_attr,
                                                 const int* __restrict__ edge_index,
                                                 const float* __restrict__ edge_sh,
                                                 int* __restrict__ deg,
                                                 float* __restrict__ outsum) {
    __shared__ alignas(16) union {
        u16 h[64][136];                               // 17408 B (prologue: ea staging, then h; +8 pad)
        struct { float bcB[64][17]; float bcC[3][64][17]; } bc;   // 17408 B (B/C cross-wave sums)
    } ovl;
    __shared__ float sT[64][66];              // s[u][e]; epilogue: out0[e][c] (c<64<=66, verified r4)
    __shared__ float vT[3][16][66];           // v[i][u][e]; epilogue: out1 flat [e*48+cr]
    __shared__ float pT[16][66];              // INV_SQRT3*(v.sh1)[u][e]
    __shared__ float sh0_s[64];
    __shared__ float sh1_s[3][64];
    __shared__ int dst_s[64];
    __shared__ int src_s[64];

    int tid = threadIdx.x;
    int e0 = blockIdx.x * 64;
    int lane = tid & 63, wave = tid >> 6;
    int el = lane & 15, q4 = lane >> 4;

    // A-fragment double buffer + per-tile bias; issued earliest for latency
    bf8 a0[4], a1[4];
    float4 bb0, bb1;
    auto loadA = [&](int i, bf8 (&a)[4], float4& bb) {
        int g = (i < 20) ? 64 + i : (i < 84 ? i - 20 : i);   // phase order B,C,A,D
        int pn = 4 * g + wave;
        const u16* gp = w2s + (size_t)pn * 2048 + lane * 8;
        a[0] = *(const bf8*)(gp);
        a[1] = *(const bf8*)(gp + 512);
        a[2] = *(const bf8*)(gp + 1024);
        a[3] = *(const bf8*)(gp + 1536);
        bb = *(const float4*)(b2 + pn * 16 + q4 * 4);
    };
    loadA(0, a0, bb0);   // prefetch first tile under the whole prologue

    // phase 1: edge meta (+ deg histogram, moved here from k_prep)
    if (tid < 64) {
        int ge = e0 + tid;
        int s = edge_index[ge];
        src_s[tid] = s;
        atomicAdd(&deg[s], 1);
        dst_s[tid] = edge_index[E_EDGES + ge];
        float4 sh = *(const float4*)(edge_sh + (size_t)ge * 4);
        sh0_s[tid] = sh.x; sh1_s[0][tid] = sh.y; sh1_s[1][tid] = sh.z; sh1_s[2][tid] = sh.w;
    }
    __syncthreads();

    // phase 2: node features (transposed into LDS) + ea tile bf16 into ovl.h
    {
        int e = tid >> 2, q = tid & 3;
        int dst = dst_s[e];
        const float* xp = node_attr + (size_t)dst * 112;
#pragma unroll
        for (int i = 0; i < 4; i++) {
            float4 f = *(const float4*)(xp + q * 16 + i * 4);
            int u = q * 16 + i * 4;
            sT[u + 0][e] = f.x; sT[u + 1][e] = f.y; sT[u + 2][e] = f.z; sT[u + 3][e] = f.w;
        }
        float vv[12];
#pragma unroll
        for (int i = 0; i < 3; i++) {
            float4 f = *(const float4*)(xp + 64 + q * 12 + i * 4);
            vv[i * 4 + 0] = f.x; vv[i * 4 + 1] = f.y; vv[i * 4 + 2] = f.z; vv[i * 4 + 3] = f.w;
        }
        float s1x = sh1_s[0][e], s1y = sh1_s[1][e], s1z = sh1_s[2][e];
#pragma unroll
        for (int u = 0; u < 4; u++) {
            float xa = vv[u * 3 + 0], xb = vv[u * 3 + 1], xc = vv[u * 3 + 2];
            int uu = q * 4 + u;
            vT[0][uu][e] = xa; vT[1][uu][e] = xb; vT[2][uu][e] = xc;
            pT[uu][e] = INV_SQRT3_CONST * (xa * s1x + xb * s1y + xc * s1z);
        }
        // ea staging: 32 cols per thread, f32 -> bf16
        const float4* src = (const float4*)(ea + (size_t)(e0 + e) * 128 + q * 32);
#pragma unroll
        for (int i = 0; i < 8; i++) {
            float4 f = src[i];
            int c = q * 32 + i * 4;
            ovl.h[e][c + 0] = f2bf(f.x); ovl.h[e][c + 1] = f2bf(f.y);
            ovl.h[e][c + 2] = f2bf(f.z); ovl.h[e][c + 3] = f2bf(f.w);
        }
    }
    __syncthreads();

    // phase 3: h = relu(ea@W1+b1) — k_h's MFMA block verbatim (ea read from ovl.h, stride 136)
    {
        f4 hacc[4][2];
#pragma unroll
        for (int m = 0; m < 4; m++)
#pragma unroll
            for (int nt = 0; nt < 2; nt++) hacc[m][nt] = (f4){0.f, 0.f, 0.f, 0.f};
#pragma unroll
        for (int ks = 0; ks < 4; ks++) {
            bf8 a[4], b[2];
#pragma unroll
            for (int m = 0; m < 4; m++) a[m] = *(const bf8*)&ovl.h[m * 16 + el][ks * 32 + q4 * 8];
#pragma unroll
            for (int nt = 0; nt < 2; nt++) {
                int n = wave * 32 + nt * 16 + el;
                b[nt] = *(const bf8*)(w1t + n * 128 + ks * 32 + q4 * 8);
            }
#pragma unroll
            for (int m = 0; m < 4; m++)
#pragma unroll
                for (int nt = 0; nt < 2; nt++)
                    hacc[m][nt] = __builtin_amdgcn_mfma_f32_16x16x32_bf16(a[m], b[nt], hacc[m][nt], 0, 0, 0);
        }
        __syncthreads();   // all ea reads done -> safe to overwrite ovl.h with h
#pragma unroll
        for (int m = 0; m < 4; m++)
#pragma unroll
            for (int nt = 0; nt < 2; nt++) {
                int n = wave * 32 + nt * 16 + el;
                float bias = b1[n];
#pragma unroll
                for (int r = 0; r < 4; r++) {
                    int e = m * 16 + q4 * 4 + r;
                    ovl.h[e][n] = f2bf(fmaxf(hacc[m][nt][r] + bias, 0.f));
                }
            }
    }
    __syncthreads();

    // h B-fragments for ALL 4 edge-groups (64 VGPRs) + per-lane sh0 factors
    bf8 hbf[4][4];
#pragma unroll
    for (int nt = 0; nt < 4; nt++)
#pragma unroll
        for (int ks = 0; ks < 4; ks++)
            hbf[nt][ks] = *(const bf8*)&ovl.h[nt * 16 + el][ks * 32 + q4 * 8];
    float sh0n4[4];
#pragma unroll
    for (int nt = 0; nt < 4; nt++) sh0n4[nt] = sh0_s[nt * 16 + el];
    __syncthreads();   // everyone done reading ovl.h -> becomes bc scratch

    // zero bc scratch (17408B = 4352 floats)
    for (int idx = tid; idx < 4352; idx += 256) ((float*)&ovl.bc)[idx] = 0.f;
    __syncthreads();   // bc zeroed before any wave's atomics

    auto mfmaG = [&](const bf8 (&a)[4], const float4& bb, f4 (&wf)[4]) {
#pragma unroll
        for (int nt = 0; nt < 4; nt++) wf[nt] = (f4){bb.x, bb.y, bb.z, bb.w};
#pragma unroll
        for (int ks = 0; ks < 4; ks++)
#pragma unroll
            for (int nt = 0; nt < 4; nt++)
                wf[nt] = __builtin_amdgcn_mfma_f32_16x16x32_bf16(a[ks], hbf[nt][ks], wf[nt], 0, 0, 0);
    };
    // result layout per lane: wf[nt][r] = w[edge = nt*16+el][col-in-tile = q4*4+r]

#define STEP(INXT, ACUR, BBCUR, ANXT, BBNXT, CON) \
    { if ((INXT) < 100) loadA((INXT), ANXT, BBNXT); mfmaG(ACUR, BBCUR, wf); CON; }

    f4 wf[4];

    // ---- B phase (i=0..15, g=64+i, u=4*i+wave; out col w = q4*4+r)
    {
        f4 accBn[4];
#pragma unroll
        for (int nt = 0; nt < 4; nt++) accBn[nt] = (f4){0.f, 0.f, 0.f, 0.f};
        auto conB = [&](int ib) {
            int u = 4 * ib + wave;
#pragma unroll
            for (int nt = 0; nt < 4; nt++) {
                float f = sT[u][nt * 16 + el];
                accBn[nt] += f * wf[nt];
            }
        };
        for (int ii = 0; ii < 16; ii += 2) {
            STEP(ii + 1, a0, bb0, a1, bb1, conB(ii));
            STEP(ii + 2, a1, bb1, a0, bb0, conB(ii + 1));
        }
#pragma unroll
        for (int nt = 0; nt < 4; nt++)
#pragma unroll
            for (int r = 0; r < 4; r++)
                atomicAdd(&ovl.bc.bcB[nt * 16 + el][q4 * 4 + r], accBn[nt][r]);
    }

    // ---- C phase (i=16..19, g=80+(i-16), u=4*(i-16)+wave)
    {
        f4 accCn[3][4];
#pragma unroll
        for (int i3 = 0; i3 < 3; i3++)
#pragma unroll
            for (int nt = 0; nt < 4; nt++) accCn[i3][nt] = (f4){0.f, 0.f, 0.f, 0.f};
        auto conC = [&](int ic) {
            int u = 4 * ic + wave;
#pragma unroll
            for (int nt = 0; nt < 4; nt++) {
#pragma unroll
                for (int i3 = 0; i3 < 3; i3++) {
                    float f = vT[i3][u][nt * 16 + el];
                    accCn[i3][nt] += f * wf[nt];
                }
            }
        };
        for (int ii = 0; ii < 4; ii += 2) {
            STEP(16 + ii + 1, a0, bb0, a1, bb1, conC(ii));
            STEP(16 + ii + 2, a1, bb1, a0, bb0, conC(ii + 1));
        }
#pragma unroll
        for (int i3 = 0; i3 < 3; i3++)
#pragma unroll
            for (int nt = 0; nt < 4; nt++)
#pragma unroll
                for (int r = 0; r < 4; r++)
                    atomicAdd(&ovl.bc.bcC[i3][nt * 16 + el][q4 * 4 + r], accCn[i3][nt][r]);
    }

    // ---- A phase (i=20..83, g=i-20=u) then D phase (i=84..99, u=i-84); both -> acc0n
    f4 acc0n[4];
#pragma unroll
    for (int nt = 0; nt < 4; nt++) acc0n[nt] = (f4){0.f, 0.f, 0.f, 0.f};
    {
        auto conA = [&](int ia) {
#pragma unroll
            for (int nt = 0; nt < 4; nt++) {
                float f = sh0n4[nt] * sT[ia][nt * 16 + el];
                acc0n[nt] += f * wf[nt];
            }
        };
        for (int ii = 0; ii < 64; ii += 2) {
            STEP(20 + ii + 1, a0, bb0, a1, bb1, conA(ii));
            STEP(20 + ii + 2, a1, bb1, a0, bb0, conA(ii + 1));
        }
        auto conD = [&](int id_) {
#pragma unroll
            for (int nt = 0; nt < 4; nt++) {
                float f = pT[id_][nt * 16 + el];
                acc0n[nt] += f * wf[nt];
            }
        };
        for (int ii = 0; ii < 16; ii += 2) {
            STEP(84 + ii + 1, a0, bb0, a1, bb1, conD(ii));
            STEP(84 + ii + 2, a1, bb1, a0, bb0, conD(ii + 1));
        }
    }
#undef STEP

    __syncthreads();   // loop reads of sT/vT/pT done; all bc atomics landed

    // out0 -> sT[e][c]: wave owns col block wave*16 (A/D cols), all 64 edges
#pragma unroll
    for (int nt = 0; nt < 4; nt++)
#pragma unroll
        for (int r = 0; r < 4; r++)
            sT[nt * 16 + el][wave * 16 + q4 * 4 + r] = N0_CONST * acc0n[nt][r];
    // out1 assembly from bc sums -> vflat [e*48 + w*3 + i]
    {
        float* vflat = (float*)vT;
        for (int idx = tid; idx < 3072; idx += 256) {
            int e = idx / 48;
            int rem = idx - e * 48;
            int w = rem / 3;
            int i3 = rem - w * 3;
            vflat[idx] = N0_CONST * (ovl.bc.bcB[e][w] * sh1_s[i3][e] + ovl.bc.bcC[i3][e][w] * sh0_s[e]);
        }
    }
    __syncthreads();

    // ATOMIC scatter of the 64x112 tile into out[src*112 + c] (device-scope, L2-resident 1.8MB)
    {
        const float* vflat = (const float*)vT;
        for (int idx = tid; idx < 64 * 112; idx += 256) {
            int e = idx / 112;
            int c = idx - e * 112;
            float val = (c < 64) ? sT[e][c] : vflat[e * 48 + (c - 64)];
            atomicAdd(&outsum[(size_t)src_s[e] * 112 + c], val);
        }
    }
}

// Final: out = out_sum/max(deg,1) + node_attr. Block = node, thread = col.
__global__ __launch_bounds__(128) void k_fin(const int* __restrict__ deg,
                                             const float* __restrict__ node_attr,
                                             float* __restrict__ out) {
    int n = blockIdx.x;
    int c = threadIdx.x;
    if (c >= 112) return;
    float d = fmaxf((float)deg[n], 1.f);
    out[n * 112 + c] = out[n * 112 + c] / d + node_attr[n * 112 + c];
}

extern "C" void kernel_launch(void* const* d_in, const int* in_sizes, int n_in,
                              void* d_out, int out_size, void* d_ws, size_t ws_size,
                              hipStream_t stream) {
    const float* node_attr  = (const float*)d_in[0];
    const int*   edge_index = (const int*)d_in[1];
    const float* edge_attr  = (const float*)d_in[2];
    const float* edge_sh    = (const float*)d_in[3];
    const float* W1         = (const float*)d_in[6];
    const float* b1         = (const float*)d_in[7];
    const float* W2         = (const float*)d_in[8];
    const float* b2         = (const float*)d_in[9];
    float* out = (float*)d_out;

    char* ws = (char*)d_ws;
    u16*   w2s    = (u16*)ws;                     // 6400*128*2  = 1,638,400
    u16*   w1t    = (u16*)(ws + 1638400);         // 128*128*2   =    32,768
    int*   deg    = (int*)(ws + 1671168);         // 4096*4

    k_prep<<<473, 256, 0, stream>>>(W2, W1, w2s, w1t, deg, out);
    k_main<<<512, 256, 0, stream>>>(w2s, w1t, b1, edge_attr, b2, node_attr, edge_index, edge_sh, deg, out);
    k_fin<<<4096, 128, 0, stream>>>(deg, node_attr, out);
}